// Round 3
// baseline (20230.513 us; speedup 1.0000x reference)
//
#include <hip/hip_runtime.h>
#include <hip/hip_bf16.h>

// ---------------------------------------------------------------------------
// IEGMN layer, MI355X round-2: FP32 in/out (reference dtype), fp32 math.
//   zero_kernel : zero the atomic-accumulator region of ws
//   edge_kernel : gather + RBF + edge MLP + coords MLP + atomic seg-sums
//   proj_kernel : q/k/v projections -> fp32 ws
//   attn_kernel : flash attention (no split-K), fp32
//   coords_fin  : x_ev = 0.25*orig + 0.75*coords + xsum/max(cnt,1) -> out
//   node_kernel : node MLP (576->256->256) + skip -> out
// ---------------------------------------------------------------------------

#define N_LIG   4096
#define N_REC   16384
#define E_LIG_N 65536
#define E_REC_N 262144
#define HD      256
#define ORIGD   64
#define EFD     16
#define NSIG    15
#define EIN     543      // 2*HD + EFD + NSIG

__device__ __forceinline__ float lrelu(float x) { return x > 0.f ? x : 0.01f * x; }

// ---------------------------------------------------------------------------
__global__ void zero_kernel(float* __restrict__ p, int n) {
    int i = blockIdx.x * 256 + threadIdx.x;
    if (i < n) p[i] = 0.f;
}

// ---------------------------------------------------------------------------
// Edge kernel: 16 edges per block, 256 threads.
__global__ __launch_bounds__(256) void edge_kernel(
    const float* __restrict__ coords,
    const float* __restrict__ h,
    const float* __restrict__ ef,
    const int* __restrict__ src, const int* __restrict__ dst,
    const float* __restrict__ W1, const float* __restrict__ b1,
    const float* __restrict__ W2, const float* __restrict__ b2,
    const float* __restrict__ Wc1, const float* __restrict__ bc1,
    const float* __restrict__ Wc2, const float* __restrict__ bc2,
    float* __restrict__ aggr, float* __restrict__ cnt, float* __restrict__ xsum)
{
    __shared__ float sIn[16][EIN + 1];    // also reused as sMsg[16][256]
    __shared__ float sHid[16][HD];
    __shared__ float sXrel[16][3];
    __shared__ int   sSrc[16], sDst[16];
    __shared__ float sRed[16];

    const int tid = threadIdx.x;
    const int e0  = blockIdx.x * 16;

    if (tid < 16) {
        const int e = e0 + tid;
        const int s = src[e], d = dst[e];
        sSrc[tid] = s; sDst[tid] = d;
        float d2 = 0.f;
        #pragma unroll
        for (int c = 0; c < 3; ++c) {
            float xr = coords[s * 3 + c] - coords[d * 3 + c];
            sXrel[tid][c] = xr;
            d2 += xr * xr;
        }
        float sig = 1.0f;
        #pragma unroll
        for (int si = 0; si < NSIG; ++si) {
            sIn[tid][2 * HD + EFD + si] = __expf(-d2 / sig);
            sig *= 1.5f;
        }
    }
    __syncthreads();

    for (int e = 0; e < 16; ++e) {
        const int s = sSrc[e], d = sDst[e];
        const int eg = e0 + e;
        for (int i = tid; i < 2 * HD + EFD; i += 256) {
            float v;
            if (i < HD)            v = h[(size_t)s * HD + i];
            else if (i < 2 * HD)   v = h[(size_t)d * HD + (i - HD)];
            else                   v = ef[(size_t)eg * EFD + (i - 2 * HD)];
            sIn[e][i] = v;
        }
    }
    __syncthreads();

    float acc[16];

    // layer 1: 543 -> 256, leaky relu
    {
        const float bj = b1[tid];
        #pragma unroll
        for (int e = 0; e < 16; ++e) acc[e] = bj;
        for (int k = 0; k < EIN; ++k) {
            const float w = W1[(size_t)k * HD + tid];
            #pragma unroll
            for (int e = 0; e < 16; ++e) acc[e] += sIn[e][k] * w;
        }
        #pragma unroll
        for (int e = 0; e < 16; ++e) sHid[e][tid] = lrelu(acc[e]);
    }
    __syncthreads();

    // layer 2: 256 -> 256 (msg), atomic aggregate
    {
        const float bj = b2[tid];
        #pragma unroll
        for (int e = 0; e < 16; ++e) acc[e] = bj;
        for (int k = 0; k < HD; ++k) {
            const float w = W2[(size_t)k * HD + tid];
            #pragma unroll
            for (int e = 0; e < 16; ++e) acc[e] += sHid[e][k] * w;
        }
    }
    float* sMsg = &sIn[0][0];   // sIn dead after layer-1 barrier
    #pragma unroll
    for (int e = 0; e < 16; ++e) {
        sMsg[e * HD + tid] = acc[e];
        atomicAdd(&aggr[(size_t)sDst[e] * HD + tid], acc[e]);
    }
    if (tid < 16) sRed[tid] = bc2[0];
    __syncthreads();

    // coords MLP: 256 -> 256 (lrelu) -> 1
    {
        const float bj  = bc1[tid];
        const float wc2 = Wc2[tid];
        #pragma unroll
        for (int e = 0; e < 16; ++e) acc[e] = bj;
        for (int k = 0; k < HD; ++k) {
            const float w = Wc1[(size_t)k * HD + tid];
            #pragma unroll
            for (int e = 0; e < 16; ++e) acc[e] += sMsg[e * HD + k] * w;
        }
        #pragma unroll
        for (int e = 0; e < 16; ++e) acc[e] = lrelu(acc[e]) * wc2;
    }
    #pragma unroll
    for (int e = 0; e < 16; ++e) {
        float v = acc[e];
        #pragma unroll
        for (int off = 32; off > 0; off >>= 1) v += __shfl_xor(v, off);
        if ((tid & 63) == 0) atomicAdd(&sRed[e], v);
    }
    __syncthreads();
    if (tid < 16) {
        const float p = sRed[tid];
        const int d = sDst[tid];
        #pragma unroll
        for (int c = 0; c < 3; ++c)
            atomicAdd(&xsum[(size_t)d * 3 + c], sXrel[tid][c] * p);
        atomicAdd(&cnt[d], 1.0f);
    }
}

// ---------------------------------------------------------------------------
// q/k/v projection: out[N,256] = (lrelu?)(X[N,256] @ W[256,256]), fp32.
__global__ __launch_bounds__(256) void proj_kernel(
    const float* __restrict__ X, const float* __restrict__ W,
    float* __restrict__ out, int applyLrelu)
{
    __shared__ float sIn[16][HD];
    const int tid = threadIdx.x;
    const int r0  = blockIdx.x * 16;
    for (int r = 0; r < 16; ++r)
        sIn[r][tid] = X[(size_t)(r0 + r) * HD + tid];
    __syncthreads();
    float acc[16];
    #pragma unroll
    for (int r = 0; r < 16; ++r) acc[r] = 0.f;
    for (int k = 0; k < HD; ++k) {
        const float w = W[(size_t)k * HD + tid];
        #pragma unroll
        for (int r = 0; r < 16; ++r) acc[r] += sIn[r][k] * w;
    }
    #pragma unroll
    for (int r = 0; r < 16; ++r) {
        float v = acc[r];
        if (applyLrelu) v = lrelu(v);
        out[(size_t)(r0 + r) * HD + tid] = v;
    }
}

// ---------------------------------------------------------------------------
// Flash attention, no split-K. 16 rows/block (4 waves x 4 rows), fused norm.
#define TNK 16
__global__ __launch_bounds__(256) void attn_kernel(
    const float* __restrict__ Q, const float* __restrict__ K,
    const float* __restrict__ V, const float* __restrict__ mask,
    float* __restrict__ Out, int nKeys, int transposed)
{
    __shared__ float4 sK[TNK][64];
    __shared__ float4 sV[TNK][64];
    __shared__ float  sM[16][TNK];
    const int tid  = threadIdx.x;
    const int lane = tid & 63;
    const int wave = tid >> 6;
    const int R0   = blockIdx.x * 16;          // block's first q-row
    const int r0   = R0 + wave * 4;            // wave's first q-row

    const float4* Qv = reinterpret_cast<const float4*>(Q);
    const float4* Kv = reinterpret_cast<const float4*>(K);
    const float4* Vv = reinterpret_cast<const float4*>(V);

    float4 q4[4];
    #pragma unroll
    for (int r = 0; r < 4; ++r)
        q4[r] = Qv[(size_t)(r0 + r) * 64 + lane];

    float m[4], l[4];
    float4 o[4];
    #pragma unroll
    for (int r = 0; r < 4; ++r) {
        m[r] = -INFINITY; l[r] = 0.f;
        o[r].x = o[r].y = o[r].z = o[r].w = 0.f;
    }

    for (int j0 = 0; j0 < nKeys; j0 += TNK) {
        __syncthreads();
        for (int idx = tid; idx < TNK * 64; idx += 256) {
            const int row = idx >> 6, col = idx & 63;
            sK[row][col] = Kv[(size_t)(j0 + row) * 64 + col];
            sV[row][col] = Vv[(size_t)(j0 + row) * 64 + col];
        }
        {
            const int row = tid / TNK, col = tid % TNK;   // 256 = 16*TNK exactly
            sM[row][col] = transposed
                ? mask[(size_t)(j0 + col) * N_REC + (R0 + row)]
                : mask[(size_t)(R0 + row) * N_REC + (j0 + col)];
        }
        __syncthreads();

        for (int jj = 0; jj < TNK; ++jj) {
            const float4 k4 = sK[jj][lane];
            float p[4];
            #pragma unroll
            for (int r = 0; r < 4; ++r)
                p[r] = q4[r].x * k4.x + q4[r].y * k4.y + q4[r].z * k4.z + q4[r].w * k4.w;
            #pragma unroll
            for (int off = 32; off > 0; off >>= 1) {
                #pragma unroll
                for (int r = 0; r < 4; ++r) p[r] += __shfl_xor(p[r], off);
            }
            const float4 v4 = sV[jj][lane];
            #pragma unroll
            for (int r = 0; r < 4; ++r) {
                const float mv = sM[wave * 4 + r][jj];
                const float a  = mv * p[r] - 1000.f * (1.f - mv);
                const float mn = fmaxf(m[r], a);
                const float c  = __expf(m[r] - mn);   // m=-inf first iter -> 0
                const float w  = __expf(a - mn);
                l[r]   = l[r] * c + w;
                o[r].x = o[r].x * c + w * v4.x;
                o[r].y = o[r].y * c + w * v4.y;
                o[r].z = o[r].z * c + w * v4.z;
                o[r].w = o[r].w * c + w * v4.w;
                m[r]   = mn;
            }
        }
    }

    #pragma unroll
    for (int r = 0; r < 4; ++r) {
        const float inv = 1.f / l[r];
        float4 ov;
        ov.x = o[r].x * inv; ov.y = o[r].y * inv;
        ov.z = o[r].z * inv; ov.w = o[r].w * inv;
        *reinterpret_cast<float4*>(&Out[(size_t)(r0 + r) * HD + lane * 4]) = ov;
    }
}

// ---------------------------------------------------------------------------
__global__ void coords_fin(
    const float* __restrict__ coords, const float* __restrict__ origc,
    const float* __restrict__ xsum, const float* __restrict__ cnt,
    float* __restrict__ out, int n)
{
    const int i = blockIdx.x * 256 + threadIdx.x;
    if (i >= n * 3) return;
    const int node = i / 3;
    const float inv = 1.f / fmaxf(cnt[node], 1.f);
    out[i] = 0.25f * origc[i] + 0.75f * coords[i] + xsum[i] * inv;
}

// ---------------------------------------------------------------------------
// Node MLP: in = [aggr_mean(256) | cross(256) | orig(64)] -> 256 -> 256, skip.
__global__ __launch_bounds__(256) void node_kernel(
    const float* __restrict__ aggr, const float* __restrict__ cnt,
    const float* __restrict__ cross, const float* __restrict__ orig,
    const float* __restrict__ hfeat,
    const float* __restrict__ W1, const float* __restrict__ b1,
    const float* __restrict__ W2, const float* __restrict__ b2,
    float* __restrict__ out)
{
    const int NIN = 2 * HD + ORIGD;   // 576
    __shared__ float sIn[16][2 * HD + ORIGD + 1];
    __shared__ float sHid[16][HD];
    __shared__ float sInv[16];
    const int tid = threadIdx.x;
    const int r0  = blockIdx.x * 16;

    if (tid < 16) sInv[tid] = 1.f / fmaxf(cnt[r0 + tid], 1.f);
    __syncthreads();

    for (int r = 0; r < 16; ++r) {
        const int row = r0 + r;
        for (int i = tid; i < NIN; i += 256) {
            float v;
            if (i < HD)            v = aggr[(size_t)row * HD + i] * sInv[r];
            else if (i < 2 * HD)   v = cross[(size_t)row * HD + (i - HD)];
            else                   v = orig[(size_t)row * ORIGD + (i - 2 * HD)];
            sIn[r][i] = v;
        }
    }
    __syncthreads();

    float acc[16];
    {
        const float bj = b1[tid];
        #pragma unroll
        for (int r = 0; r < 16; ++r) acc[r] = bj;
        for (int k = 0; k < NIN; ++k) {
            const float w = W1[(size_t)k * HD + tid];
            #pragma unroll
            for (int r = 0; r < 16; ++r) acc[r] += sIn[r][k] * w;
        }
        #pragma unroll
        for (int r = 0; r < 16; ++r) sHid[r][tid] = lrelu(acc[r]);
    }
    __syncthreads();
    {
        const float bj = b2[tid];
        #pragma unroll
        for (int r = 0; r < 16; ++r) acc[r] = bj;
        for (int k = 0; k < HD; ++k) {
            const float w = W2[(size_t)k * HD + tid];
            #pragma unroll
            for (int r = 0; r < 16; ++r) acc[r] += sHid[r][k] * w;
        }
    }
    #pragma unroll
    for (int r = 0; r < 16; ++r) {
        const int row = r0 + r;
        out[(size_t)row * HD + tid] = 0.5f * acc[r] + 0.5f * hfeat[(size_t)row * HD + tid];
    }
}

// ---------------------------------------------------------------------------
extern "C" void kernel_launch(void* const* d_in, const int* in_sizes, int n_in,
                              void* d_out, int out_size, void* d_ws, size_t ws_size,
                              hipStream_t stream)
{
    const float* coords_lig = (const float*)d_in[0];
    const float* h_lig      = (const float*)d_in[1];
    const float* orig_lig   = (const float*)d_in[2];
    const float* origc_lig  = (const float*)d_in[3];
    const float* coords_rec = (const float*)d_in[4];
    const float* h_rec      = (const float*)d_in[5];
    const float* orig_rec   = (const float*)d_in[6];
    const float* origc_rec  = (const float*)d_in[7];
    const float* mask       = (const float*)d_in[8];
    const float* lig_ef     = (const float*)d_in[9];
    const float* rec_ef     = (const float*)d_in[10];
    const int* lig_src = (const int*)d_in[11];
    const int* lig_dst = (const int*)d_in[12];
    const int* rec_src = (const int*)d_in[13];
    const int* rec_dst = (const int*)d_in[14];
    const float* le_w1 = (const float*)d_in[15];
    const float* le_b1 = (const float*)d_in[16];
    const float* le_w2 = (const float*)d_in[17];
    const float* le_b2 = (const float*)d_in[18];
    const float* re_w1 = (const float*)d_in[19];
    const float* re_b1 = (const float*)d_in[20];
    const float* re_w2 = (const float*)d_in[21];
    const float* re_b2 = (const float*)d_in[22];
    const float* aql_w = (const float*)d_in[23];
    const float* akl_w = (const float*)d_in[24];
    const float* avl_w = (const float*)d_in[25];
    const float* aqr_w = (const float*)d_in[26];
    const float* akr_w = (const float*)d_in[27];
    const float* avr_w = (const float*)d_in[28];
    const float* nl_w1 = (const float*)d_in[29];
    const float* nl_b1 = (const float*)d_in[30];
    const float* nl_w2 = (const float*)d_in[31];
    const float* nl_b2 = (const float*)d_in[32];
    const float* nr_w1 = (const float*)d_in[33];
    const float* nr_b1 = (const float*)d_in[34];
    const float* nr_w2 = (const float*)d_in[35];
    const float* nr_b2 = (const float*)d_in[36];
    const float* cl_w1 = (const float*)d_in[37];
    const float* cl_b1 = (const float*)d_in[38];
    const float* cl_w2 = (const float*)d_in[39];
    const float* cl_b2 = (const float*)d_in[40];
    const float* cr_w1 = (const float*)d_in[41];
    const float* cr_b1 = (const float*)d_in[42];
    const float* cr_w2 = (const float*)d_in[43];
    const float* cr_b2 = (const float*)d_in[44];

    float* out = (float*)d_out;
    float* ws  = (float*)d_ws;

    // ---- fp32 workspace layout (floats) ----
    const size_t AGGRL = 0;
    const size_t AGGRR = AGGRL + (size_t)N_LIG * HD;
    const size_t CNTL  = AGGRR + (size_t)N_REC * HD;
    const size_t CNTR  = CNTL + N_LIG;
    const size_t XSUML = CNTR + N_REC;
    const size_t XSUMR = XSUML + (size_t)N_LIG * 3;
    const size_t ZEND  = XSUMR + (size_t)N_REC * 3;          // zeroed region
    const size_t QL  = ZEND;
    const size_t KL  = QL + (size_t)N_LIG * HD;
    const size_t VL  = KL + (size_t)N_LIG * HD;
    const size_t QR  = VL + (size_t)N_LIG * HD;
    const size_t KR  = QR + (size_t)N_REC * HD;
    const size_t VR  = KR + (size_t)N_REC * HD;
    const size_t CRL = VR + (size_t)N_REC * HD;
    const size_t CRR = CRL + (size_t)N_LIG * HD;
    // end = CRR + N_REC*HD = 26,296,320 floats = ~100.3 MB

    // output element offsets (fp32)
    const size_t O_XL = 0;
    const size_t O_HL = O_XL + (size_t)N_LIG * 3;
    const size_t O_XR = O_HL + (size_t)N_LIG * HD;
    const size_t O_HR = O_XR + (size_t)N_REC * 3;

    // 1) zero atomic accumulators
    zero_kernel<<<((int)ZEND + 255) / 256, 256, 0, stream>>>(ws, (int)ZEND);

    // 2) edge kernels
    edge_kernel<<<E_LIG_N / 16, 256, 0, stream>>>(
        coords_lig, h_lig, lig_ef, lig_src, lig_dst,
        le_w1, le_b1, le_w2, le_b2, cl_w1, cl_b1, cl_w2, cl_b2,
        ws + AGGRL, ws + CNTL, ws + XSUML);
    edge_kernel<<<E_REC_N / 16, 256, 0, stream>>>(
        coords_rec, h_rec, rec_ef, rec_src, rec_dst,
        re_w1, re_b1, re_w2, re_b2, cr_w1, cr_b1, cr_w2, cr_b2,
        ws + AGGRR, ws + CNTR, ws + XSUMR);

    // 3) attention projections
    proj_kernel<<<N_LIG / 16, 256, 0, stream>>>(h_lig, aql_w, ws + QL, 1);
    proj_kernel<<<N_LIG / 16, 256, 0, stream>>>(h_lig, akl_w, ws + KL, 1);
    proj_kernel<<<N_LIG / 16, 256, 0, stream>>>(h_lig, avl_w, ws + VL, 0);
    proj_kernel<<<N_REC / 16, 256, 0, stream>>>(h_rec, aqr_w, ws + QR, 1);
    proj_kernel<<<N_REC / 16, 256, 0, stream>>>(h_rec, akr_w, ws + KR, 1);
    proj_kernel<<<N_REC / 16, 256, 0, stream>>>(h_rec, avr_w, ws + VR, 0);

    // 4) cross attention
    attn_kernel<<<N_LIG / 16, 256, 0, stream>>>(
        ws + QL, ws + KR, ws + VR, mask, ws + CRL, N_REC, 0);
    attn_kernel<<<N_REC / 16, 256, 0, stream>>>(
        ws + QR, ws + KL, ws + VL, mask, ws + CRR, N_LIG, 1);

    // 5) coordinate outputs
    coords_fin<<<(N_LIG * 3 + 255) / 256, 256, 0, stream>>>(
        coords_lig, origc_lig, ws + XSUML, ws + CNTL, out + O_XL, N_LIG);
    coords_fin<<<(N_REC * 3 + 255) / 256, 256, 0, stream>>>(
        coords_rec, origc_rec, ws + XSUMR, ws + CNTR, out + O_XR, N_REC);

    // 6) node MLPs
    node_kernel<<<N_LIG / 16, 256, 0, stream>>>(
        ws + AGGRL, ws + CNTL, ws + CRL, orig_lig, h_lig,
        nl_w1, nl_b1, nl_w2, nl_b2, out + O_HL);
    node_kernel<<<N_REC / 16, 256, 0, stream>>>(
        ws + AGGRR, ws + CNTR, ws + CRR, orig_rec, h_rec,
        nr_w1, nr_b1, nr_w2, nr_b2, out + O_HR);

    (void)in_sizes; (void)n_in; (void)out_size; (void)ws_size;
}

// Round 4
// 5935.529 us; speedup vs baseline: 3.4084x; 3.4084x over previous
//
#include <hip/hip_runtime.h>
#include <hip/hip_bf16.h>

// ---------------------------------------------------------------------------
// IEGMN layer, MI355X round-4: MFMA flash attention (bf16), rest fp32.
//   zero_kernel  : zero atomic accumulators
//   edge_kernel  : gather + RBF + edge MLP + coords MLP + atomic seg-sums
//   proj_kernel  : q/k/v projections -> bf16 ws
//   attn_mfma    : flash attention partial (split-K), MFMA 16x16x32 bf16
//   attn_combine : merge splits -> bf16 cross features
//   coords_fin   : x_ev -> out (fp32)
//   node_kernel  : node MLP + skip -> out (fp32)
// ---------------------------------------------------------------------------

#define N_LIG   4096
#define N_REC   16384
#define E_LIG_N 65536
#define E_REC_N 262144
#define HD      256
#define ORIGD   64
#define EFD     16
#define NSIG    15
#define EIN     543      // 2*HD + EFD + NSIG

typedef __bf16 bf16x8 __attribute__((ext_vector_type(8)));
typedef float  f32x4  __attribute__((ext_vector_type(4)));

__device__ __forceinline__ float lrelu(float x) { return x > 0.f ? x : 0.01f * x; }
__device__ __forceinline__ float bf2f(__hip_bfloat16 x) { return __bfloat162float(x); }
__device__ __forceinline__ unsigned short f2bu(float f) {
    __hip_bfloat16 h = __float2bfloat16(f);
    return *reinterpret_cast<unsigned short*>(&h);
}

// ---------------------------------------------------------------------------
__global__ void zero_kernel(float* __restrict__ p, int n) {
    int i = blockIdx.x * 256 + threadIdx.x;
    if (i < n) p[i] = 0.f;
}

// ---------------------------------------------------------------------------
// Edge kernel: 16 edges per block, 256 threads. (unchanged from round-2 pass)
__global__ __launch_bounds__(256) void edge_kernel(
    const float* __restrict__ coords,
    const float* __restrict__ h,
    const float* __restrict__ ef,
    const int* __restrict__ src, const int* __restrict__ dst,
    const float* __restrict__ W1, const float* __restrict__ b1,
    const float* __restrict__ W2, const float* __restrict__ b2,
    const float* __restrict__ Wc1, const float* __restrict__ bc1,
    const float* __restrict__ Wc2, const float* __restrict__ bc2,
    float* __restrict__ aggr, float* __restrict__ cnt, float* __restrict__ xsum)
{
    __shared__ float sIn[16][EIN + 1];    // reused as sMsg[16][256]
    __shared__ float sHid[16][HD];
    __shared__ float sXrel[16][3];
    __shared__ int   sSrc[16], sDst[16];
    __shared__ float sRed[16];

    const int tid = threadIdx.x;
    const int e0  = blockIdx.x * 16;

    if (tid < 16) {
        const int e = e0 + tid;
        const int s = src[e], d = dst[e];
        sSrc[tid] = s; sDst[tid] = d;
        float d2 = 0.f;
        #pragma unroll
        for (int c = 0; c < 3; ++c) {
            float xr = coords[s * 3 + c] - coords[d * 3 + c];
            sXrel[tid][c] = xr;
            d2 += xr * xr;
        }
        float sig = 1.0f;
        #pragma unroll
        for (int si = 0; si < NSIG; ++si) {
            sIn[tid][2 * HD + EFD + si] = __expf(-d2 / sig);
            sig *= 1.5f;
        }
    }
    __syncthreads();

    for (int e = 0; e < 16; ++e) {
        const int s = sSrc[e], d = sDst[e];
        const int eg = e0 + e;
        for (int i = tid; i < 2 * HD + EFD; i += 256) {
            float v;
            if (i < HD)            v = h[(size_t)s * HD + i];
            else if (i < 2 * HD)   v = h[(size_t)d * HD + (i - HD)];
            else                   v = ef[(size_t)eg * EFD + (i - 2 * HD)];
            sIn[e][i] = v;
        }
    }
    __syncthreads();

    float acc[16];

    {
        const float bj = b1[tid];
        #pragma unroll
        for (int e = 0; e < 16; ++e) acc[e] = bj;
        for (int k = 0; k < EIN; ++k) {
            const float w = W1[(size_t)k * HD + tid];
            #pragma unroll
            for (int e = 0; e < 16; ++e) acc[e] += sIn[e][k] * w;
        }
        #pragma unroll
        for (int e = 0; e < 16; ++e) sHid[e][tid] = lrelu(acc[e]);
    }
    __syncthreads();

    {
        const float bj = b2[tid];
        #pragma unroll
        for (int e = 0; e < 16; ++e) acc[e] = bj;
        for (int k = 0; k < HD; ++k) {
            const float w = W2[(size_t)k * HD + tid];
            #pragma unroll
            for (int e = 0; e < 16; ++e) acc[e] += sHid[e][k] * w;
        }
    }
    float* sMsg = &sIn[0][0];
    #pragma unroll
    for (int e = 0; e < 16; ++e) {
        sMsg[e * HD + tid] = acc[e];
        atomicAdd(&aggr[(size_t)sDst[e] * HD + tid], acc[e]);
    }
    if (tid < 16) sRed[tid] = bc2[0];
    __syncthreads();

    {
        const float bj  = bc1[tid];
        const float wc2 = Wc2[tid];
        #pragma unroll
        for (int e = 0; e < 16; ++e) acc[e] = bj;
        for (int k = 0; k < HD; ++k) {
            const float w = Wc1[(size_t)k * HD + tid];
            #pragma unroll
            for (int e = 0; e < 16; ++e) acc[e] += sMsg[e * HD + k] * w;
        }
        #pragma unroll
        for (int e = 0; e < 16; ++e) acc[e] = lrelu(acc[e]) * wc2;
    }
    #pragma unroll
    for (int e = 0; e < 16; ++e) {
        float v = acc[e];
        #pragma unroll
        for (int off = 32; off > 0; off >>= 1) v += __shfl_xor(v, off);
        if ((tid & 63) == 0) atomicAdd(&sRed[e], v);
    }
    __syncthreads();
    if (tid < 16) {
        const float p = sRed[tid];
        const int d = sDst[tid];
        #pragma unroll
        for (int c = 0; c < 3; ++c)
            atomicAdd(&xsum[(size_t)d * 3 + c], sXrel[tid][c] * p);
        atomicAdd(&cnt[d], 1.0f);
    }
}

// ---------------------------------------------------------------------------
// q/k/v projection: out[N,256] = (lrelu?)(X @ W) -> bf16.
__global__ __launch_bounds__(256) void proj_kernel(
    const float* __restrict__ X, const float* __restrict__ W,
    __hip_bfloat16* __restrict__ out, int applyLrelu)
{
    __shared__ float sIn[16][HD];
    const int tid = threadIdx.x;
    const int r0  = blockIdx.x * 16;
    for (int r = 0; r < 16; ++r)
        sIn[r][tid] = X[(size_t)(r0 + r) * HD + tid];
    __syncthreads();
    float acc[16];
    #pragma unroll
    for (int r = 0; r < 16; ++r) acc[r] = 0.f;
    for (int k = 0; k < HD; ++k) {
        const float w = W[(size_t)k * HD + tid];
        #pragma unroll
        for (int r = 0; r < 16; ++r) acc[r] += sIn[r][k] * w;
    }
    #pragma unroll
    for (int r = 0; r < 16; ++r) {
        float v = acc[r];
        if (applyLrelu) v = lrelu(v);
        out[(size_t)(r0 + r) * HD + tid] = __float2bfloat16(v);
    }
}

// ---------------------------------------------------------------------------
// MFMA flash attention partial. 64 q-rows/block (4 waves x 16), 32-key tiles.
// Q,K,V bf16; softmax fp32; partial O (unnormalized) fp32 + running m,l.
__global__ __launch_bounds__(256, 2) void attn_mfma(
    const __hip_bfloat16* __restrict__ Qb, const __hip_bfloat16* __restrict__ Kb,
    const __hip_bfloat16* __restrict__ Vb, const float* __restrict__ maskG,
    float* __restrict__ PO, float* __restrict__ PM, float* __restrict__ PL,
    int M, int chunkKeys, int transposed)
{
    __shared__ unsigned short sK[32][264];    // [key][dim], +8 pad
    __shared__ unsigned short sVt[256][40];   // [dim][key], +8 pad
    __shared__ unsigned short sP[4][16][40];  // per-wave P tile, +8 pad
    __shared__ float          sMask[64][36];  // [blockrow][key], +4 pad

    const int tid  = threadIdx.x;
    const int lane = tid & 63;
    const int wave = tid >> 6;
    const int col  = lane & 15;
    const int quad = lane >> 4;
    const int R0   = blockIdx.x * 64;
    const int split = blockIdx.y;
    const int jbase = split * chunkKeys;

    // Q fragments (A-operand): row = wave*16 + col, k-slices of 32
    bf16x8 qf[8];
    {
        const __hip_bfloat16* qp =
            Qb + (size_t)(R0 + wave * 16 + col) * HD + quad * 8;
        #pragma unroll
        for (int s = 0; s < 8; ++s)
            qf[s] = *reinterpret_cast<const bf16x8*>(qp + 32 * s);
    }

    f32x4 o[16];
    #pragma unroll
    for (int dt = 0; dt < 16; ++dt) { o[dt][0]=0.f; o[dt][1]=0.f; o[dt][2]=0.f; o[dt][3]=0.f; }
    float m[4], l[4];
    #pragma unroll
    for (int r = 0; r < 4; ++r) { m[r] = -INFINITY; l[r] = 0.f; }

    for (int jt = 0; jt < chunkKeys; jt += 32) {
        const int j0 = jbase + jt;
        __syncthreads();
        // ---- stage K [32][256] (row-major, b128) ----
        {
            const int key = tid >> 3;
            const int d0  = (tid & 7) * 32;
            const __hip_bfloat16* kp = Kb + (size_t)(j0 + key) * HD + d0;
            #pragma unroll
            for (int i = 0; i < 4; ++i)
                *reinterpret_cast<uint4*>(&sK[key][d0 + 8 * i]) =
                    *reinterpret_cast<const uint4*>(kp + 8 * i);
        }
        // ---- stage V transposed -> sVt[dim][key] ----
        {
            const int key = tid & 31;
            const int d0  = (tid >> 5) * 32;
            const __hip_bfloat16* vp = Vb + (size_t)(j0 + key) * HD + d0;
            #pragma unroll
            for (int i = 0; i < 4; ++i) {
                unsigned short tmp[8];
                *reinterpret_cast<uint4*>(tmp) = *reinterpret_cast<const uint4*>(vp + 8 * i);
                #pragma unroll
                for (int u = 0; u < 8; ++u)
                    sVt[d0 + 8 * i + u][key] = tmp[u];
            }
        }
        // ---- stage mask tile [64 rows][32 keys] ----
        if (!transposed) {
            const int row = tid >> 2;
            const int c0  = (tid & 3) * 8;
            #pragma unroll
            for (int i = 0; i < 2; ++i)
                *reinterpret_cast<float4*>(&sMask[row][c0 + 4 * i]) =
                    *reinterpret_cast<const float4*>(
                        &maskG[(size_t)(R0 + row) * N_REC + j0 + c0 + 4 * i]);
        } else {
            const int key = tid >> 3;
            const int r0m = (tid & 7) * 8;
            #pragma unroll
            for (int i = 0; i < 2; ++i) {
                float tmp[4];
                *reinterpret_cast<float4*>(tmp) =
                    *reinterpret_cast<const float4*>(
                        &maskG[(size_t)(j0 + key) * N_REC + R0 + r0m + 4 * i]);
                #pragma unroll
                for (int u = 0; u < 4; ++u)
                    sMask[r0m + 4 * i + u][key] = tmp[u];
            }
        }
        __syncthreads();

        // ---- S = Q K^T (two 16-key tiles, 8 k-slices) ----
        f32x4 sacc[2];
        sacc[0][0]=0.f; sacc[0][1]=0.f; sacc[0][2]=0.f; sacc[0][3]=0.f;
        sacc[1][0]=0.f; sacc[1][1]=0.f; sacc[1][2]=0.f; sacc[1][3]=0.f;
        #pragma unroll
        for (int t = 0; t < 2; ++t) {
            #pragma unroll
            for (int s = 0; s < 8; ++s) {
                bf16x8 kf = *reinterpret_cast<const bf16x8*>(
                    &sK[col + 16 * t][32 * s + quad * 8]);
                sacc[t] = __builtin_amdgcn_mfma_f32_16x16x32_bf16(qf[s], kf, sacc[t], 0, 0, 0);
            }
        }

        // ---- online softmax; rows = wave*16 + quad*4 + r ----
        float a[2][4];
        #pragma unroll
        for (int t = 0; t < 2; ++t)
            #pragma unroll
            for (int r = 0; r < 4; ++r) {
                const float mv = sMask[wave * 16 + quad * 4 + r][col + 16 * t];
                a[t][r] = mv * sacc[t][r] - 1000.f * (1.f - mv);
            }
        #pragma unroll
        for (int r = 0; r < 4; ++r) {
            float mx = fmaxf(a[0][r], a[1][r]);
            #pragma unroll
            for (int off = 1; off < 16; off <<= 1)
                mx = fmaxf(mx, __shfl_xor(mx, off));
            const float mn = fmaxf(m[r], mx);
            const float c  = __expf(m[r] - mn);
            m[r] = mn;
            const float p0 = __expf(a[0][r] - mn);
            const float p1 = __expf(a[1][r] - mn);
            sP[wave][quad * 4 + r][col]      = f2bu(p0);
            sP[wave][quad * 4 + r][col + 16] = f2bu(p1);
            float ps = p0 + p1;
            #pragma unroll
            for (int off = 1; off < 16; off <<= 1)
                ps += __shfl_xor(ps, off);
            l[r] = l[r] * c + ps;
            #pragma unroll
            for (int dt = 0; dt < 16; ++dt) o[dt][r] *= c;
        }

        // ---- O += P V (A-frag of P via LDS; B-frag from sVt) ----
        bf16x8 pf = *reinterpret_cast<const bf16x8*>(&sP[wave][col][quad * 8]);
        #pragma unroll
        for (int dt = 0; dt < 16; ++dt) {
            bf16x8 vf = *reinterpret_cast<const bf16x8*>(
                &sVt[col + 16 * dt][quad * 8]);
            o[dt] = __builtin_amdgcn_mfma_f32_16x16x32_bf16(pf, vf, o[dt], 0, 0, 0);
        }
    }

    // ---- epilogue: partial (unnormalized) O, running m, l ----
    #pragma unroll
    for (int dt = 0; dt < 16; ++dt)
        #pragma unroll
        for (int r = 0; r < 4; ++r) {
            const int row = R0 + wave * 16 + quad * 4 + r;
            PO[((size_t)split * M + row) * HD + dt * 16 + col] = o[dt][r];
        }
    if (col == 0) {
        #pragma unroll
        for (int r = 0; r < 4; ++r) {
            const int row = R0 + wave * 16 + quad * 4 + r;
            PM[(size_t)split * M + row] = m[r];
            PL[(size_t)split * M + row] = l[r];
        }
    }
}

// ---------------------------------------------------------------------------
__global__ void attn_combine(
    const float* __restrict__ PO, const float* __restrict__ PM,
    const float* __restrict__ PL, __hip_bfloat16* __restrict__ Out,
    int M, int nchunks)
{
    const int idx = blockIdx.x * 256 + threadIdx.x;   // row*256 + d
    const int row = idx >> 8;
    float mmax = -INFINITY;
    for (int c = 0; c < nchunks; ++c) mmax = fmaxf(mmax, PM[(size_t)c * M + row]);
    float denom = 0.f, acc = 0.f;
    for (int c = 0; c < nchunks; ++c) {
        const float w = __expf(PM[(size_t)c * M + row] - mmax);
        denom += PL[(size_t)c * M + row] * w;
        acc   += PO[(size_t)c * M * HD + idx] * w;
    }
    Out[idx] = __float2bfloat16(acc / denom);
}

// ---------------------------------------------------------------------------
__global__ void coords_fin(
    const float* __restrict__ coords, const float* __restrict__ origc,
    const float* __restrict__ xsum, const float* __restrict__ cnt,
    float* __restrict__ out, int n)
{
    const int i = blockIdx.x * 256 + threadIdx.x;
    if (i >= n * 3) return;
    const int node = i / 3;
    const float inv = 1.f / fmaxf(cnt[node], 1.f);
    out[i] = 0.25f * origc[i] + 0.75f * coords[i] + xsum[i] * inv;
}

// ---------------------------------------------------------------------------
// Node MLP: [aggr_mean(256) | cross(256,bf16) | orig(64)] -> 256 -> 256, skip.
__global__ __launch_bounds__(256) void node_kernel(
    const float* __restrict__ aggr, const float* __restrict__ cnt,
    const __hip_bfloat16* __restrict__ cross, const float* __restrict__ orig,
    const float* __restrict__ hfeat,
    const float* __restrict__ W1, const float* __restrict__ b1,
    const float* __restrict__ W2, const float* __restrict__ b2,
    float* __restrict__ out)
{
    const int NIN = 2 * HD + ORIGD;   // 576
    __shared__ float sIn[16][2 * HD + ORIGD + 1];
    __shared__ float sHid[16][HD];
    __shared__ float sInv[16];
    const int tid = threadIdx.x;
    const int r0  = blockIdx.x * 16;

    if (tid < 16) sInv[tid] = 1.f / fmaxf(cnt[r0 + tid], 1.f);
    __syncthreads();

    for (int r = 0; r < 16; ++r) {
        const int row = r0 + r;
        for (int i = tid; i < NIN; i += 256) {
            float v;
            if (i < HD)            v = aggr[(size_t)row * HD + i] * sInv[r];
            else if (i < 2 * HD)   v = bf2f(cross[(size_t)row * HD + (i - HD)]);
            else                   v = orig[(size_t)row * ORIGD + (i - 2 * HD)];
            sIn[r][i] = v;
        }
    }
    __syncthreads();

    float acc[16];
    {
        const float bj = b1[tid];
        #pragma unroll
        for (int r = 0; r < 16; ++r) acc[r] = bj;
        for (int k = 0; k < NIN; ++k) {
            const float w = W1[(size_t)k * HD + tid];
            #pragma unroll
            for (int r = 0; r < 16; ++r) acc[r] += sIn[r][k] * w;
        }
        #pragma unroll
        for (int r = 0; r < 16; ++r) sHid[r][tid] = lrelu(acc[r]);
    }
    __syncthreads();
    {
        const float bj = b2[tid];
        #pragma unroll
        for (int r = 0; r < 16; ++r) acc[r] = bj;
        for (int k = 0; k < HD; ++k) {
            const float w = W2[(size_t)k * HD + tid];
            #pragma unroll
            for (int r = 0; r < 16; ++r) acc[r] += sHid[r][k] * w;
        }
    }
    #pragma unroll
    for (int r = 0; r < 16; ++r) {
        const int row = r0 + r;
        out[(size_t)row * HD + tid] = 0.5f * acc[r] + 0.5f * hfeat[(size_t)row * HD + tid];
    }
}

// ---------------------------------------------------------------------------
extern "C" void kernel_launch(void* const* d_in, const int* in_sizes, int n_in,
                              void* d_out, int out_size, void* d_ws, size_t ws_size,
                              hipStream_t stream)
{
    const float* coords_lig = (const float*)d_in[0];
    const float* h_lig      = (const float*)d_in[1];
    const float* orig_lig   = (const float*)d_in[2];
    const float* origc_lig  = (const float*)d_in[3];
    const float* coords_rec = (const float*)d_in[4];
    const float* h_rec      = (const float*)d_in[5];
    const float* orig_rec   = (const float*)d_in[6];
    const float* origc_rec  = (const float*)d_in[7];
    const float* mask       = (const float*)d_in[8];
    const float* lig_ef     = (const float*)d_in[9];
    const float* rec_ef     = (const float*)d_in[10];
    const int* lig_src = (const int*)d_in[11];
    const int* lig_dst = (const int*)d_in[12];
    const int* rec_src = (const int*)d_in[13];
    const int* rec_dst = (const int*)d_in[14];
    const float* le_w1 = (const float*)d_in[15];
    const float* le_b1 = (const float*)d_in[16];
    const float* le_w2 = (const float*)d_in[17];
    const float* le_b2 = (const float*)d_in[18];
    const float* re_w1 = (const float*)d_in[19];
    const float* re_b1 = (const float*)d_in[20];
    const float* re_w2 = (const float*)d_in[21];
    const float* re_b2 = (const float*)d_in[22];
    const float* aql_w = (const float*)d_in[23];
    const float* akl_w = (const float*)d_in[24];
    const float* avl_w = (const float*)d_in[25];
    const float* aqr_w = (const float*)d_in[26];
    const float* akr_w = (const float*)d_in[27];
    const float* avr_w = (const float*)d_in[28];
    const float* nl_w1 = (const float*)d_in[29];
    const float* nl_b1 = (const float*)d_in[30];
    const float* nl_w2 = (const float*)d_in[31];
    const float* nl_b2 = (const float*)d_in[32];
    const float* nr_w1 = (const float*)d_in[33];
    const float* nr_b1 = (const float*)d_in[34];
    const float* nr_w2 = (const float*)d_in[35];
    const float* nr_b2 = (const float*)d_in[36];
    const float* cl_w1 = (const float*)d_in[37];
    const float* cl_b1 = (const float*)d_in[38];
    const float* cl_w2 = (const float*)d_in[39];
    const float* cl_b2 = (const float*)d_in[40];
    const float* cr_w1 = (const float*)d_in[41];
    const float* cr_b1 = (const float*)d_in[42];
    const float* cr_w2 = (const float*)d_in[43];
    const float* cr_b2 = (const float*)d_in[44];

    float* out = (float*)d_out;
    float* wsf = (float*)d_ws;

    // ---- fp32 zone ----
    const size_t AGGRL = 0;
    const size_t AGGRR = AGGRL + (size_t)N_LIG * HD;
    const size_t CNTL  = AGGRR + (size_t)N_REC * HD;
    const size_t CNTR  = CNTL + N_LIG;
    const size_t XSUML = CNTR + N_REC;
    const size_t XSUMR = XSUML + (size_t)N_LIG * 3;
    const size_t ZEND  = XSUMR + (size_t)N_REC * 3;          // zeroed region
    const size_t PO_   = ZEND;                                // 8*4096*256 == 2*16384*256
    const size_t PM_   = PO_ + (size_t)8 * N_LIG * HD;
    const size_t PL_   = PM_ + (size_t)8 * N_LIG;
    const size_t FEND  = PL_ + (size_t)8 * N_LIG;

    // ---- bf16 zone ----
    __hip_bfloat16* wsb = (__hip_bfloat16*)(wsf + FEND);
    const size_t QL  = 0;
    const size_t KL  = QL + (size_t)N_LIG * HD;
    const size_t VL  = KL + (size_t)N_LIG * HD;
    const size_t QR  = VL + (size_t)N_LIG * HD;
    const size_t KR  = QR + (size_t)N_REC * HD;
    const size_t VR  = KR + (size_t)N_REC * HD;
    const size_t CRL = VR + (size_t)N_REC * HD;
    const size_t CRR = CRL + (size_t)N_LIG * HD;
    // total ws ~ 97 MB

    const size_t O_XL = 0;
    const size_t O_HL = O_XL + (size_t)N_LIG * 3;
    const size_t O_XR = O_HL + (size_t)N_LIG * HD;
    const size_t O_HR = O_XR + (size_t)N_REC * 3;

    // 1) zero atomic accumulators
    zero_kernel<<<((int)ZEND + 255) / 256, 256, 0, stream>>>(wsf, (int)ZEND);

    // 2) edge kernels
    edge_kernel<<<E_LIG_N / 16, 256, 0, stream>>>(
        coords_lig, h_lig, lig_ef, lig_src, lig_dst,
        le_w1, le_b1, le_w2, le_b2, cl_w1, cl_b1, cl_w2, cl_b2,
        wsf + AGGRL, wsf + CNTL, wsf + XSUML);
    edge_kernel<<<E_REC_N / 16, 256, 0, stream>>>(
        coords_rec, h_rec, rec_ef, rec_src, rec_dst,
        re_w1, re_b1, re_w2, re_b2, cr_w1, cr_b1, cr_w2, cr_b2,
        wsf + AGGRR, wsf + CNTR, wsf + XSUMR);

    // 3) projections -> bf16
    proj_kernel<<<N_LIG / 16, 256, 0, stream>>>(h_lig, aql_w, wsb + QL, 1);
    proj_kernel<<<N_LIG / 16, 256, 0, stream>>>(h_lig, akl_w, wsb + KL, 1);
    proj_kernel<<<N_LIG / 16, 256, 0, stream>>>(h_lig, avl_w, wsb + VL, 0);
    proj_kernel<<<N_REC / 16, 256, 0, stream>>>(h_rec, aqr_w, wsb + QR, 1);
    proj_kernel<<<N_REC / 16, 256, 0, stream>>>(h_rec, akr_w, wsb + KR, 1);
    proj_kernel<<<N_REC / 16, 256, 0, stream>>>(h_rec, avr_w, wsb + VR, 0);

    // 4) MFMA flash attention, split-K + combine (PO/PM/PL reused)
    {
        dim3 gl(N_LIG / 64, 8);    // 8 splits of 2048 rec keys
        attn_mfma<<<gl, 256, 0, stream>>>(wsb + QL, wsb + KR, wsb + VR, mask,
                                          wsf + PO_, wsf + PM_, wsf + PL_,
                                          N_LIG, N_REC / 8, 0);
        attn_combine<<<N_LIG, 256, 0, stream>>>(
            wsf + PO_, wsf + PM_, wsf + PL_, wsb + CRL, N_LIG, 8);

        dim3 gr(N_REC / 64, 2);    // 2 splits of 2048 lig keys
        attn_mfma<<<gr, 256, 0, stream>>>(wsb + QR, wsb + KL, wsb + VL, mask,
                                          wsf + PO_, wsf + PM_, wsf + PL_,
                                          N_REC, N_LIG / 2, 1);
        attn_combine<<<N_REC, 256, 0, stream>>>(
            wsf + PO_, wsf + PM_, wsf + PL_, wsb + CRR, N_REC, 2);
    }

    // 5) coordinate outputs
    coords_fin<<<(N_LIG * 3 + 255) / 256, 256, 0, stream>>>(
        coords_lig, origc_lig, wsf + XSUML, wsf + CNTL, out + O_XL, N_LIG);
    coords_fin<<<(N_REC * 3 + 255) / 256, 256, 0, stream>>>(
        coords_rec, origc_rec, wsf + XSUMR, wsf + CNTR, out + O_XR, N_REC);

    // 6) node MLPs
    node_kernel<<<N_LIG / 16, 256, 0, stream>>>(
        wsf + AGGRL, wsf + CNTL, wsb + CRL, orig_lig, h_lig,
        nl_w1, nl_b1, nl_w2, nl_b2, out + O_HL);
    node_kernel<<<N_REC / 16, 256, 0, stream>>>(
        wsf + AGGRR, wsf + CNTR, wsb + CRR, orig_rec, h_rec,
        nr_w1, nr_b1, nr_w2, nr_b2, out + O_HR);

    (void)in_sizes; (void)n_in; (void)out_size; (void)ws_size;
}

// Round 5
// 2222.386 us; speedup vs baseline: 9.1031x; 2.6708x over previous
//
#include <hip/hip_runtime.h>
#include <hip/hip_bf16.h>

// ---------------------------------------------------------------------------
// IEGMN layer, MI355X round-5: MFMA edge/node MLPs + MFMA attention.
//   zero_kernel  : zero atomic accumulators
//   wt_kernel    : transpose+cast weights fp32[K][256] -> bf16[256][KP]
//   edge_mfma    : gather + RBF + edge MLP + coords MLP + atomic seg-sums (MFMA)
//   proj_kernel  : q/k/v projections -> bf16 ws
//   attn_mfma    : flash attention partial (split-K), MFMA 16x16x32 bf16
//   attn_combine : merge splits -> bf16 cross features
//   coords_fin   : x_ev -> out (fp32)
//   node_mfma    : node MLP + skip -> out (fp32, MFMA)
// ---------------------------------------------------------------------------

#define N_LIG   4096
#define N_REC   16384
#define E_LIG_N 65536
#define E_REC_N 262144
#define HD      256
#define ORIGD   64
#define EFD     16
#define NSIG    15
#define EIN     543      // 2*HD + EFD + NSIG
#define EKP     544      // padded K for edge layer 1
#define NKP     576      // node layer-1 K (exact)
#define XP      552      // sX LDS pitch (bf16 elems)
#define HP      264      // sH LDS pitch
#define XPN     584      // node sX pitch

typedef __bf16 bf16x8 __attribute__((ext_vector_type(8)));
typedef float  f32x4  __attribute__((ext_vector_type(4)));

__device__ __forceinline__ float lrelu(float x) { return x > 0.f ? x : 0.01f * x; }
__device__ __forceinline__ float bf2f(__hip_bfloat16 x) { return __bfloat162float(x); }
__device__ __forceinline__ unsigned short f2bu(float f) {
    __hip_bfloat16 h = __float2bfloat16(f);
    return *reinterpret_cast<unsigned short*>(&h);
}

// ---------------------------------------------------------------------------
__global__ void zero_kernel(float* __restrict__ p, int n) {
    int i = blockIdx.x * 256 + threadIdx.x;
    if (i < n) p[i] = 0.f;
}

// ---------------------------------------------------------------------------
// Transpose + cast: src fp32 [K][256] -> dst bf16 [256][KP] (zero-padded).
__global__ void wt_kernel(const float* __restrict__ src,
                          __hip_bfloat16* __restrict__ dst, int K, int KP) {
    const int n = blockIdx.x;             // 256 blocks
    for (int k = threadIdx.x; k < KP; k += 256) {
        const float v = (k < K) ? src[(size_t)k * 256 + n] : 0.f;
        dst[(size_t)n * KP + k] = __float2bfloat16(v);
    }
}

// ---------------------------------------------------------------------------
// Edge MFMA kernel: 32 edges/block, 256 threads (4 waves x 64-col strips).
__global__ __launch_bounds__(256) void edge_mfma(
    const float* __restrict__ coords, const float* __restrict__ h,
    const float* __restrict__ ef,
    const int* __restrict__ src, const int* __restrict__ dst,
    const __hip_bfloat16* __restrict__ W1t,   // [256][544]
    const float* __restrict__ b1,
    const __hip_bfloat16* __restrict__ W2t,   // [256][256]
    const float* __restrict__ b2,
    const __hip_bfloat16* __restrict__ Wc1t,  // [256][256]
    const float* __restrict__ bc1,
    const float* __restrict__ wc2v, const float* __restrict__ bc2,
    float* __restrict__ aggr, float* __restrict__ cnt, float* __restrict__ xsum)
{
    __shared__ unsigned short sX[32][XP];   // layer-1 input; reused for msg
    __shared__ unsigned short sH[32][HP];   // hidden
    __shared__ float sXrel[32][3];
    __shared__ int   sDst[32];
    __shared__ float sRedW[4][32];

    const int tid  = threadIdx.x;
    const int lane = tid & 63;
    const int wave = tid >> 6;
    const int col  = lane & 15;
    const int quad = lane >> 4;
    const int e0   = blockIdx.x * 32;

    // ---- gather h_src | h_dst (cols 0..511) ----
    for (int i = tid; i < 32 * 128; i += 256) {
        const int row = i >> 7, c4 = i & 127;
        const int node = (c4 < 64) ? src[e0 + row] : dst[e0 + row];
        const float4 v = *reinterpret_cast<const float4*>(
            &h[(size_t)node * HD + (c4 & 63) * 4]);
        ushort4 u = { f2bu(v.x), f2bu(v.y), f2bu(v.z), f2bu(v.w) };
        *reinterpret_cast<ushort4*>(&sX[row][c4 * 4]) = u;
    }
    // ---- ef (cols 512..527) ----
    if (tid < 128) {
        const int row = tid >> 2, c = tid & 3;
        const float4 v = *reinterpret_cast<const float4*>(
            &ef[(size_t)(e0 + row) * EFD + c * 4]);
        ushort4 u = { f2bu(v.x), f2bu(v.y), f2bu(v.z), f2bu(v.w) };
        *reinterpret_cast<ushort4*>(&sX[row][512 + c * 4]) = u;
    }
    // ---- rbf (cols 528..542), pad 543, xrel, dst ----
    if (tid < 32) {
        const int e = e0 + tid;
        const int s = src[e], d = dst[e];
        sDst[tid] = d;
        float d2 = 0.f;
        #pragma unroll
        for (int c = 0; c < 3; ++c) {
            const float xr = coords[s * 3 + c] - coords[d * 3 + c];
            sXrel[tid][c] = xr;
            d2 += xr * xr;
        }
        float sig = 1.0f;
        #pragma unroll
        for (int si = 0; si < NSIG; ++si) {
            sX[tid][528 + si] = f2bu(__expf(-d2 / sig));
            sig *= 1.5f;
        }
        sX[tid][543] = 0;
    }
    __syncthreads();

    f32x4 acc[2][4];

    // ---- layer 1: 544 -> 256, lrelu -> sH ----
    #pragma unroll
    for (int nt = 0; nt < 4; ++nt) {
        const float bv = b1[wave * 64 + nt * 16 + col];
        acc[0][nt] = { bv, bv, bv, bv };
        acc[1][nt] = { bv, bv, bv, bv };
    }
    for (int ks = 0; ks < EKP / 32; ++ks) {
        const bf16x8 a0 = *reinterpret_cast<const bf16x8*>(&sX[col][ks * 32 + quad * 8]);
        const bf16x8 a1 = *reinterpret_cast<const bf16x8*>(&sX[16 + col][ks * 32 + quad * 8]);
        #pragma unroll
        for (int nt = 0; nt < 4; ++nt) {
            const int n = wave * 64 + nt * 16 + col;
            const bf16x8 b = *reinterpret_cast<const bf16x8*>(
                &W1t[(size_t)n * EKP + ks * 32 + quad * 8]);
            acc[0][nt] = __builtin_amdgcn_mfma_f32_16x16x32_bf16(a0, b, acc[0][nt], 0, 0, 0);
            acc[1][nt] = __builtin_amdgcn_mfma_f32_16x16x32_bf16(a1, b, acc[1][nt], 0, 0, 0);
        }
    }
    #pragma unroll
    for (int mt = 0; mt < 2; ++mt)
        #pragma unroll
        for (int nt = 0; nt < 4; ++nt)
            #pragma unroll
            for (int r = 0; r < 4; ++r)
                sH[mt * 16 + quad * 4 + r][wave * 64 + nt * 16 + col] =
                    f2bu(lrelu(acc[mt][nt][r]));
    __syncthreads();

    // ---- layer 2: 256 -> 256 (msg): aggr atomics + msg -> sX ----
    #pragma unroll
    for (int nt = 0; nt < 4; ++nt) {
        const float bv = b2[wave * 64 + nt * 16 + col];
        acc[0][nt] = { bv, bv, bv, bv };
        acc[1][nt] = { bv, bv, bv, bv };
    }
    for (int ks = 0; ks < 8; ++ks) {
        const bf16x8 a0 = *reinterpret_cast<const bf16x8*>(&sH[col][ks * 32 + quad * 8]);
        const bf16x8 a1 = *reinterpret_cast<const bf16x8*>(&sH[16 + col][ks * 32 + quad * 8]);
        #pragma unroll
        for (int nt = 0; nt < 4; ++nt) {
            const int n = wave * 64 + nt * 16 + col;
            const bf16x8 b = *reinterpret_cast<const bf16x8*>(
                &W2t[(size_t)n * 256 + ks * 32 + quad * 8]);
            acc[0][nt] = __builtin_amdgcn_mfma_f32_16x16x32_bf16(a0, b, acc[0][nt], 0, 0, 0);
            acc[1][nt] = __builtin_amdgcn_mfma_f32_16x16x32_bf16(a1, b, acc[1][nt], 0, 0, 0);
        }
    }
    #pragma unroll
    for (int mt = 0; mt < 2; ++mt)
        #pragma unroll
        for (int nt = 0; nt < 4; ++nt)
            #pragma unroll
            for (int r = 0; r < 4; ++r) {
                const int row = mt * 16 + quad * 4 + r;
                const int n   = wave * 64 + nt * 16 + col;
                const float v = acc[mt][nt][r];
                atomicAdd(&aggr[(size_t)sDst[row] * HD + n], v);
                sX[row][n] = f2bu(v);     // msg tile for coords MLP
            }
    __syncthreads();

    // ---- coords MLP: 256 -> 256 (lrelu) -> dot wc2 ----
    #pragma unroll
    for (int nt = 0; nt < 4; ++nt) {
        const float bv = bc1[wave * 64 + nt * 16 + col];
        acc[0][nt] = { bv, bv, bv, bv };
        acc[1][nt] = { bv, bv, bv, bv };
    }
    for (int ks = 0; ks < 8; ++ks) {
        const bf16x8 a0 = *reinterpret_cast<const bf16x8*>(&sX[col][ks * 32 + quad * 8]);
        const bf16x8 a1 = *reinterpret_cast<const bf16x8*>(&sX[16 + col][ks * 32 + quad * 8]);
        #pragma unroll
        for (int nt = 0; nt < 4; ++nt) {
            const int n = wave * 64 + nt * 16 + col;
            const bf16x8 b = *reinterpret_cast<const bf16x8*>(
                &Wc1t[(size_t)n * 256 + ks * 32 + quad * 8]);
            acc[0][nt] = __builtin_amdgcn_mfma_f32_16x16x32_bf16(a0, b, acc[0][nt], 0, 0, 0);
            acc[1][nt] = __builtin_amdgcn_mfma_f32_16x16x32_bf16(a1, b, acc[1][nt], 0, 0, 0);
        }
    }
    float w2l[4];
    #pragma unroll
    for (int nt = 0; nt < 4; ++nt) w2l[nt] = wc2v[wave * 64 + nt * 16 + col];
    #pragma unroll
    for (int mt = 0; mt < 2; ++mt) {
        float pr[4] = { 0.f, 0.f, 0.f, 0.f };
        #pragma unroll
        for (int nt = 0; nt < 4; ++nt)
            #pragma unroll
            for (int r = 0; r < 4; ++r)
                pr[r] += lrelu(acc[mt][nt][r]) * w2l[nt];
        #pragma unroll
        for (int r = 0; r < 4; ++r) {
            #pragma unroll
            for (int off = 1; off < 16; off <<= 1) pr[r] += __shfl_xor(pr[r], off);
        }
        if (col == 0)
            #pragma unroll
            for (int r = 0; r < 4; ++r)
                sRedW[wave][mt * 16 + quad * 4 + r] = pr[r];
    }
    __syncthreads();
    if (tid < 32) {
        const float p = sRedW[0][tid] + sRedW[1][tid] + sRedW[2][tid] + sRedW[3][tid] + bc2[0];
        const int d = sDst[tid];
        #pragma unroll
        for (int c = 0; c < 3; ++c)
            atomicAdd(&xsum[(size_t)d * 3 + c], sXrel[tid][c] * p);
        atomicAdd(&cnt[d], 1.0f);
    }
}

// ---------------------------------------------------------------------------
// Node MFMA kernel: 32 nodes/block. in = [aggr_mean|cross|orig] 576 -> 256 -> 256.
__global__ __launch_bounds__(256) void node_mfma(
    const float* __restrict__ aggr, const float* __restrict__ cnt,
    const __hip_bfloat16* __restrict__ cross, const float* __restrict__ orig,
    const float* __restrict__ hfeat,
    const __hip_bfloat16* __restrict__ WN1t,  // [256][576]
    const float* __restrict__ b1,
    const __hip_bfloat16* __restrict__ WN2t,  // [256][256]
    const float* __restrict__ b2,
    float* __restrict__ out)
{
    __shared__ unsigned short sXn[32][XPN];
    __shared__ unsigned short sH[32][HP];
    __shared__ float sInv[32];

    const int tid  = threadIdx.x;
    const int lane = tid & 63;
    const int wave = tid >> 6;
    const int col  = lane & 15;
    const int quad = lane >> 4;
    const int r0   = blockIdx.x * 32;

    if (tid < 32) sInv[tid] = 1.f / fmaxf(cnt[r0 + tid], 1.f);
    __syncthreads();

    // aggr (cols 0..255), scaled by 1/cnt
    for (int i = tid; i < 32 * 64; i += 256) {
        const int row = i >> 6, c4 = i & 63;
        const float inv = sInv[row];
        const float4 v = *reinterpret_cast<const float4*>(
            &aggr[(size_t)(r0 + row) * HD + c4 * 4]);
        ushort4 u = { f2bu(v.x * inv), f2bu(v.y * inv), f2bu(v.z * inv), f2bu(v.w * inv) };
        *reinterpret_cast<ushort4*>(&sXn[row][c4 * 4]) = u;
    }
    // cross (cols 256..511), already bf16
    for (int i = tid; i < 32 * 64; i += 256) {
        const int row = i >> 6, c4 = i & 63;
        const ushort4 u = *reinterpret_cast<const ushort4*>(
            &cross[(size_t)(r0 + row) * HD + c4 * 4]);
        *reinterpret_cast<ushort4*>(&sXn[row][256 + c4 * 4]) = u;
    }
    // orig (cols 512..575)
    for (int i = tid; i < 32 * 16; i += 256) {
        const int row = i >> 4, c4 = i & 15;
        const float4 v = *reinterpret_cast<const float4*>(
            &orig[(size_t)(r0 + row) * ORIGD + c4 * 4]);
        ushort4 u = { f2bu(v.x), f2bu(v.y), f2bu(v.z), f2bu(v.w) };
        *reinterpret_cast<ushort4*>(&sXn[row][512 + c4 * 4]) = u;
    }
    __syncthreads();

    f32x4 acc[2][4];

    // layer 1: 576 -> 256, lrelu
    #pragma unroll
    for (int nt = 0; nt < 4; ++nt) {
        const float bv = b1[wave * 64 + nt * 16 + col];
        acc[0][nt] = { bv, bv, bv, bv };
        acc[1][nt] = { bv, bv, bv, bv };
    }
    for (int ks = 0; ks < NKP / 32; ++ks) {
        const bf16x8 a0 = *reinterpret_cast<const bf16x8*>(&sXn[col][ks * 32 + quad * 8]);
        const bf16x8 a1 = *reinterpret_cast<const bf16x8*>(&sXn[16 + col][ks * 32 + quad * 8]);
        #pragma unroll
        for (int nt = 0; nt < 4; ++nt) {
            const int n = wave * 64 + nt * 16 + col;
            const bf16x8 b = *reinterpret_cast<const bf16x8*>(
                &WN1t[(size_t)n * NKP + ks * 32 + quad * 8]);
            acc[0][nt] = __builtin_amdgcn_mfma_f32_16x16x32_bf16(a0, b, acc[0][nt], 0, 0, 0);
            acc[1][nt] = __builtin_amdgcn_mfma_f32_16x16x32_bf16(a1, b, acc[1][nt], 0, 0, 0);
        }
    }
    #pragma unroll
    for (int mt = 0; mt < 2; ++mt)
        #pragma unroll
        for (int nt = 0; nt < 4; ++nt)
            #pragma unroll
            for (int r = 0; r < 4; ++r)
                sH[mt * 16 + quad * 4 + r][wave * 64 + nt * 16 + col] =
                    f2bu(lrelu(acc[mt][nt][r]));
    __syncthreads();

    // layer 2: 256 -> 256, skip, write out
    #pragma unroll
    for (int nt = 0; nt < 4; ++nt) {
        const float bv = b2[wave * 64 + nt * 16 + col];
        acc[0][nt] = { bv, bv, bv, bv };
        acc[1][nt] = { bv, bv, bv, bv };
    }
    for (int ks = 0; ks < 8; ++ks) {
        const bf16x8 a0 = *reinterpret_cast<const bf16x8*>(&sH[col][ks * 32 + quad * 8]);
        const bf16x8 a1 = *reinterpret_cast<const bf16x8*>(&sH[16 + col][ks * 32 + quad * 8]);
        #pragma unroll
        for (int nt = 0; nt < 4; ++nt) {
            const int n = wave * 64 + nt * 16 + col;
            const bf16x8 b = *reinterpret_cast<const bf16x8*>(
                &WN2t[(size_t)n * 256 + ks * 32 + quad * 8]);
            acc[0][nt] = __builtin_amdgcn_mfma_f32_16x16x32_bf16(a0, b, acc[0][nt], 0, 0, 0);
            acc[1][nt] = __builtin_amdgcn_mfma_f32_16x16x32_bf16(a1, b, acc[1][nt], 0, 0, 0);
        }
    }
    #pragma unroll
    for (int mt = 0; mt < 2; ++mt)
        #pragma unroll
        for (int nt = 0; nt < 4; ++nt)
            #pragma unroll
            for (int r = 0; r < 4; ++r) {
                const int g = r0 + mt * 16 + quad * 4 + r;
                const int n = wave * 64 + nt * 16 + col;
                out[(size_t)g * HD + n] =
                    0.5f * acc[mt][nt][r] + 0.5f * hfeat[(size_t)g * HD + n];
            }
}

// ---------------------------------------------------------------------------
// q/k/v projection: out[N,256] = (lrelu?)(X @ W) -> bf16.
__global__ __launch_bounds__(256) void proj_kernel(
    const float* __restrict__ X, const float* __restrict__ W,
    __hip_bfloat16* __restrict__ out, int applyLrelu)
{
    __shared__ float sIn[16][HD];
    const int tid = threadIdx.x;
    const int r0  = blockIdx.x * 16;
    for (int r = 0; r < 16; ++r)
        sIn[r][tid] = X[(size_t)(r0 + r) * HD + tid];
    __syncthreads();
    float acc[16];
    #pragma unroll
    for (int r = 0; r < 16; ++r) acc[r] = 0.f;
    for (int k = 0; k < HD; ++k) {
        const float w = W[(size_t)k * HD + tid];
        #pragma unroll
        for (int r = 0; r < 16; ++r) acc[r] += sIn[r][k] * w;
    }
    #pragma unroll
    for (int r = 0; r < 16; ++r) {
        float v = acc[r];
        if (applyLrelu) v = lrelu(v);
        out[(size_t)(r0 + r) * HD + tid] = __float2bfloat16(v);
    }
}

// ---------------------------------------------------------------------------
// MFMA flash attention partial. 64 q-rows/block (4 waves x 16), 32-key tiles.
__global__ __launch_bounds__(256, 2) void attn_mfma(
    const __hip_bfloat16* __restrict__ Qb, const __hip_bfloat16* __restrict__ Kb,
    const __hip_bfloat16* __restrict__ Vb, const float* __restrict__ maskG,
    float* __restrict__ PO, float* __restrict__ PM, float* __restrict__ PL,
    int M, int chunkKeys, int transposed)
{
    __shared__ unsigned short sK[32][264];
    __shared__ unsigned short sVt[256][40];
    __shared__ unsigned short sP[4][16][40];
    __shared__ float          sMask[64][36];

    const int tid  = threadIdx.x;
    const int lane = tid & 63;
    const int wave = tid >> 6;
    const int col  = lane & 15;
    const int quad = lane >> 4;
    const int R0   = blockIdx.x * 64;
    const int split = blockIdx.y;
    const int jbase = split * chunkKeys;

    bf16x8 qf[8];
    {
        const __hip_bfloat16* qp =
            Qb + (size_t)(R0 + wave * 16 + col) * HD + quad * 8;
        #pragma unroll
        for (int s = 0; s < 8; ++s)
            qf[s] = *reinterpret_cast<const bf16x8*>(qp + 32 * s);
    }

    f32x4 o[16];
    #pragma unroll
    for (int dt = 0; dt < 16; ++dt) { o[dt][0]=0.f; o[dt][1]=0.f; o[dt][2]=0.f; o[dt][3]=0.f; }
    float m[4], l[4];
    #pragma unroll
    for (int r = 0; r < 4; ++r) { m[r] = -INFINITY; l[r] = 0.f; }

    for (int jt = 0; jt < chunkKeys; jt += 32) {
        const int j0 = jbase + jt;
        __syncthreads();
        {
            const int key = tid >> 3;
            const int d0  = (tid & 7) * 32;
            const __hip_bfloat16* kp = Kb + (size_t)(j0 + key) * HD + d0;
            #pragma unroll
            for (int i = 0; i < 4; ++i)
                *reinterpret_cast<uint4*>(&sK[key][d0 + 8 * i]) =
                    *reinterpret_cast<const uint4*>(kp + 8 * i);
        }
        {
            const int key = tid & 31;
            const int d0  = (tid >> 5) * 32;
            const __hip_bfloat16* vp = Vb + (size_t)(j0 + key) * HD + d0;
            #pragma unroll
            for (int i = 0; i < 4; ++i) {
                unsigned short tmp[8];
                *reinterpret_cast<uint4*>(tmp) = *reinterpret_cast<const uint4*>(vp + 8 * i);
                #pragma unroll
                for (int u = 0; u < 8; ++u)
                    sVt[d0 + 8 * i + u][key] = tmp[u];
            }
        }
        if (!transposed) {
            const int row = tid >> 2;
            const int c0  = (tid & 3) * 8;
            #pragma unroll
            for (int i = 0; i < 2; ++i)
                *reinterpret_cast<float4*>(&sMask[row][c0 + 4 * i]) =
                    *reinterpret_cast<const float4*>(
                        &maskG[(size_t)(R0 + row) * N_REC + j0 + c0 + 4 * i]);
        } else {
            const int key = tid >> 3;
            const int r0m = (tid & 7) * 8;
            #pragma unroll
            for (int i = 0; i < 2; ++i) {
                float tmp[4];
                *reinterpret_cast<float4*>(tmp) =
                    *reinterpret_cast<const float4*>(
                        &maskG[(size_t)(j0 + key) * N_REC + R0 + r0m + 4 * i]);
                #pragma unroll
                for (int u = 0; u < 4; ++u)
                    sMask[r0m + 4 * i + u][key] = tmp[u];
            }
        }
        __syncthreads();

        f32x4 sacc[2];
        sacc[0][0]=0.f; sacc[0][1]=0.f; sacc[0][2]=0.f; sacc[0][3]=0.f;
        sacc[1][0]=0.f; sacc[1][1]=0.f; sacc[1][2]=0.f; sacc[1][3]=0.f;
        #pragma unroll
        for (int t = 0; t < 2; ++t) {
            #pragma unroll
            for (int s = 0; s < 8; ++s) {
                bf16x8 kf = *reinterpret_cast<const bf16x8*>(
                    &sK[col + 16 * t][32 * s + quad * 8]);
                sacc[t] = __builtin_amdgcn_mfma_f32_16x16x32_bf16(qf[s], kf, sacc[t], 0, 0, 0);
            }
        }

        float a[2][4];
        #pragma unroll
        for (int t = 0; t < 2; ++t)
            #pragma unroll
            for (int r = 0; r < 4; ++r) {
                const float mv = sMask[wave * 16 + quad * 4 + r][col + 16 * t];
                a[t][r] = mv * sacc[t][r] - 1000.f * (1.f - mv);
            }
        #pragma unroll
        for (int r = 0; r < 4; ++r) {
            float mx = fmaxf(a[0][r], a[1][r]);
            #pragma unroll
            for (int off = 1; off < 16; off <<= 1)
                mx = fmaxf(mx, __shfl_xor(mx, off));
            const float mn = fmaxf(m[r], mx);
            const float c  = __expf(m[r] - mn);
            m[r] = mn;
            const float p0 = __expf(a[0][r] - mn);
            const float p1 = __expf(a[1][r] - mn);
            sP[wave][quad * 4 + r][col]      = f2bu(p0);
            sP[wave][quad * 4 + r][col + 16] = f2bu(p1);
            float ps = p0 + p1;
            #pragma unroll
            for (int off = 1; off < 16; off <<= 1)
                ps += __shfl_xor(ps, off);
            l[r] = l[r] * c + ps;
            #pragma unroll
            for (int dt = 0; dt < 16; ++dt) o[dt][r] *= c;
        }

        bf16x8 pf = *reinterpret_cast<const bf16x8*>(&sP[wave][col][quad * 8]);
        #pragma unroll
        for (int dt = 0; dt < 16; ++dt) {
            bf16x8 vf = *reinterpret_cast<const bf16x8*>(
                &sVt[col + 16 * dt][quad * 8]);
            o[dt] = __builtin_amdgcn_mfma_f32_16x16x32_bf16(pf, vf, o[dt], 0, 0, 0);
        }
    }

    #pragma unroll
    for (int dt = 0; dt < 16; ++dt)
        #pragma unroll
        for (int r = 0; r < 4; ++r) {
            const int row = R0 + wave * 16 + quad * 4 + r;
            PO[((size_t)split * M + row) * HD + dt * 16 + col] = o[dt][r];
        }
    if (col == 0) {
        #pragma unroll
        for (int r = 0; r < 4; ++r) {
            const int row = R0 + wave * 16 + quad * 4 + r;
            PM[(size_t)split * M + row] = m[r];
            PL[(size_t)split * M + row] = l[r];
        }
    }
}

// ---------------------------------------------------------------------------
__global__ void attn_combine(
    const float* __restrict__ PO, const float* __restrict__ PM,
    const float* __restrict__ PL, __hip_bfloat16* __restrict__ Out,
    int M, int nchunks)
{
    const int idx = blockIdx.x * 256 + threadIdx.x;
    const int row = idx >> 8;
    float mmax = -INFINITY;
    for (int c = 0; c < nchunks; ++c) mmax = fmaxf(mmax, PM[(size_t)c * M + row]);
    float denom = 0.f, acc = 0.f;
    for (int c = 0; c < nchunks; ++c) {
        const float w = __expf(PM[(size_t)c * M + row] - mmax);
        denom += PL[(size_t)c * M + row] * w;
        acc   += PO[(size_t)c * M * HD + idx] * w;
    }
    Out[idx] = __float2bfloat16(acc / denom);
}

// ---------------------------------------------------------------------------
__global__ void coords_fin(
    const float* __restrict__ coords, const float* __restrict__ origc,
    const float* __restrict__ xsum, const float* __restrict__ cnt,
    float* __restrict__ out, int n)
{
    const int i = blockIdx.x * 256 + threadIdx.x;
    if (i >= n * 3) return;
    const int node = i / 3;
    const float inv = 1.f / fmaxf(cnt[node], 1.f);
    out[i] = 0.25f * origc[i] + 0.75f * coords[i] + xsum[i] * inv;
}

// ---------------------------------------------------------------------------
extern "C" void kernel_launch(void* const* d_in, const int* in_sizes, int n_in,
                              void* d_out, int out_size, void* d_ws, size_t ws_size,
                              hipStream_t stream)
{
    const float* coords_lig = (const float*)d_in[0];
    const float* h_lig      = (const float*)d_in[1];
    const float* orig_lig   = (const float*)d_in[2];
    const float* origc_lig  = (const float*)d_in[3];
    const float* coords_rec = (const float*)d_in[4];
    const float* h_rec      = (const float*)d_in[5];
    const float* orig_rec   = (const float*)d_in[6];
    const float* origc_rec  = (const float*)d_in[7];
    const float* mask       = (const float*)d_in[8];
    const float* lig_ef     = (const float*)d_in[9];
    const float* rec_ef     = (const float*)d_in[10];
    const int* lig_src = (const int*)d_in[11];
    const int* lig_dst = (const int*)d_in[12];
    const int* rec_src = (const int*)d_in[13];
    const int* rec_dst = (const int*)d_in[14];
    const float* le_w1 = (const float*)d_in[15];
    const float* le_b1 = (const float*)d_in[16];
    const float* le_w2 = (const float*)d_in[17];
    const float* le_b2 = (const float*)d_in[18];
    const float* re_w1 = (const float*)d_in[19];
    const float* re_b1 = (const float*)d_in[20];
    const float* re_w2 = (const float*)d_in[21];
    const float* re_b2 = (const float*)d_in[22];
    const float* aql_w = (const float*)d_in[23];
    const float* akl_w = (const float*)d_in[24];
    const float* avl_w = (const float*)d_in[25];
    const float* aqr_w = (const float*)d_in[26];
    const float* akr_w = (const float*)d_in[27];
    const float* avr_w = (const float*)d_in[28];
    const float* nl_w1 = (const float*)d_in[29];
    const float* nl_b1 = (const float*)d_in[30];
    const float* nl_w2 = (const float*)d_in[31];
    const float* nl_b2 = (const float*)d_in[32];
    const float* nr_w1 = (const float*)d_in[33];
    const float* nr_b1 = (const float*)d_in[34];
    const float* nr_w2 = (const float*)d_in[35];
    const float* nr_b2 = (const float*)d_in[36];
    const float* cl_w1 = (const float*)d_in[37];
    const float* cl_b1 = (const float*)d_in[38];
    const float* cl_w2 = (const float*)d_in[39];
    const float* cl_b2 = (const float*)d_in[40];
    const float* cr_w1 = (const float*)d_in[41];
    const float* cr_b1 = (const float*)d_in[42];
    const float* cr_w2 = (const float*)d_in[43];
    const float* cr_b2 = (const float*)d_in[44];

    float* out = (float*)d_out;
    float* wsf = (float*)d_ws;

    // ---- fp32 zone ----
    const size_t AGGRL = 0;
    const size_t AGGRR = AGGRL + (size_t)N_LIG * HD;
    const size_t CNTL  = AGGRR + (size_t)N_REC * HD;
    const size_t CNTR  = CNTL + N_LIG;
    const size_t XSUML = CNTR + N_REC;
    const size_t XSUMR = XSUML + (size_t)N_LIG * 3;
    const size_t ZEND  = XSUMR + (size_t)N_REC * 3;          // zeroed region
    const size_t PO_   = ZEND;                               // 8*N_LIG*HD == 2*N_REC*HD
    const size_t PM_   = PO_ + (size_t)8 * N_LIG * HD;
    const size_t PL_   = PM_ + (size_t)8 * N_LIG;
    const size_t FEND  = PL_ + (size_t)8 * N_LIG;

    // ---- bf16 zone ----
    __hip_bfloat16* wsb = (__hip_bfloat16*)(wsf + FEND);
    const size_t QL  = 0;
    const size_t KL  = QL + (size_t)N_LIG * HD;
    const size_t VL  = KL + (size_t)N_LIG * HD;
    const size_t QR  = VL + (size_t)N_LIG * HD;
    const size_t KR  = QR + (size_t)N_REC * HD;
    const size_t VR  = KR + (size_t)N_REC * HD;
    const size_t CRL = VR + (size_t)N_REC * HD;
    const size_t CRR = CRL + (size_t)N_LIG * HD;
    const size_t WT1L  = CRR + (size_t)N_REC * HD;
    const size_t WT2L  = WT1L + (size_t)256 * EKP;
    const size_t WTC1L = WT2L + (size_t)256 * 256;
    const size_t WTN1L = WTC1L + (size_t)256 * 256;
    const size_t WTN2L = WTN1L + (size_t)256 * NKP;
    const size_t WT1R  = WTN2L + (size_t)256 * 256;
    const size_t WT2R  = WT1R + (size_t)256 * EKP;
    const size_t WTC1R = WT2R + (size_t)256 * 256;
    const size_t WTN1R = WTC1R + (size_t)256 * 256;
    const size_t WTN2R = WTN1R + (size_t)256 * NKP;
    // end ≈ 99 MB total

    const size_t O_XL = 0;
    const size_t O_HL = O_XL + (size_t)N_LIG * 3;
    const size_t O_XR = O_HL + (size_t)N_LIG * HD;
    const size_t O_HR = O_XR + (size_t)N_REC * 3;

    // 1) zero atomic accumulators
    zero_kernel<<<((int)ZEND + 255) / 256, 256, 0, stream>>>(wsf, (int)ZEND);

    // 2) weight transposes (fp32 -> bf16 [256][KP])
    wt_kernel<<<256, 256, 0, stream>>>(le_w1, wsb + WT1L, EIN, EKP);
    wt_kernel<<<256, 256, 0, stream>>>(le_w2, wsb + WT2L, 256, 256);
    wt_kernel<<<256, 256, 0, stream>>>(cl_w1, wsb + WTC1L, 256, 256);
    wt_kernel<<<256, 256, 0, stream>>>(nl_w1, wsb + WTN1L, NKP, NKP);
    wt_kernel<<<256, 256, 0, stream>>>(nl_w2, wsb + WTN2L, 256, 256);
    wt_kernel<<<256, 256, 0, stream>>>(re_w1, wsb + WT1R, EIN, EKP);
    wt_kernel<<<256, 256, 0, stream>>>(re_w2, wsb + WT2R, 256, 256);
    wt_kernel<<<256, 256, 0, stream>>>(cr_w1, wsb + WTC1R, 256, 256);
    wt_kernel<<<256, 256, 0, stream>>>(nr_w1, wsb + WTN1R, NKP, NKP);
    wt_kernel<<<256, 256, 0, stream>>>(nr_w2, wsb + WTN2R, 256, 256);

    // 3) edge MFMA kernels
    edge_mfma<<<E_LIG_N / 32, 256, 0, stream>>>(
        coords_lig, h_lig, lig_ef, lig_src, lig_dst,
        wsb + WT1L, le_b1, wsb + WT2L, le_b2, wsb + WTC1L, cl_b1, cl_w2, cl_b2,
        wsf + AGGRL, wsf + CNTL, wsf + XSUML);
    edge_mfma<<<E_REC_N / 32, 256, 0, stream>>>(
        coords_rec, h_rec, rec_ef, rec_src, rec_dst,
        wsb + WT1R, re_b1, wsb + WT2R, re_b2, wsb + WTC1R, cr_b1, cr_w2, cr_b2,
        wsf + AGGRR, wsf + CNTR, wsf + XSUMR);

    // 4) projections -> bf16
    proj_kernel<<<N_LIG / 16, 256, 0, stream>>>(h_lig, aql_w, wsb + QL, 1);
    proj_kernel<<<N_LIG / 16, 256, 0, stream>>>(h_lig, akl_w, wsb + KL, 1);
    proj_kernel<<<N_LIG / 16, 256, 0, stream>>>(h_lig, avl_w, wsb + VL, 0);
    proj_kernel<<<N_REC / 16, 256, 0, stream>>>(h_rec, aqr_w, wsb + QR, 1);
    proj_kernel<<<N_REC / 16, 256, 0, stream>>>(h_rec, akr_w, wsb + KR, 1);
    proj_kernel<<<N_REC / 16, 256, 0, stream>>>(h_rec, avr_w, wsb + VR, 0);

    // 5) MFMA flash attention, split-K + combine
    {
        dim3 gl(N_LIG / 64, 8);
        attn_mfma<<<gl, 256, 0, stream>>>(wsb + QL, wsb + KR, wsb + VR, mask,
                                          wsf + PO_, wsf + PM_, wsf + PL_,
                                          N_LIG, N_REC / 8, 0);
        attn_combine<<<N_LIG, 256, 0, stream>>>(
            wsf + PO_, wsf + PM_, wsf + PL_, wsb + CRL, N_LIG, 8);

        dim3 gr(N_REC / 64, 2);
        attn_mfma<<<gr, 256, 0, stream>>>(wsb + QR, wsb + KL, wsb + VL, mask,
                                          wsf + PO_, wsf + PM_, wsf + PL_,
                                          N_REC, N_LIG / 2, 1);
        attn_combine<<<N_REC, 256, 0, stream>>>(
            wsf + PO_, wsf + PM_, wsf + PL_, wsb + CRR, N_REC, 2);
    }

    // 6) coordinate outputs
    coords_fin<<<(N_LIG * 3 + 255) / 256, 256, 0, stream>>>(
        coords_lig, origc_lig, wsf + XSUML, wsf + CNTL, out + O_XL, N_LIG);
    coords_fin<<<(N_REC * 3 + 255) / 256, 256, 0, stream>>>(
        coords_rec, origc_rec, wsf + XSUMR, wsf + CNTR, out + O_XR, N_REC);

    // 7) node MFMA kernels
    node_mfma<<<N_LIG / 32, 256, 0, stream>>>(
        wsf + AGGRL, wsf + CNTL, wsb + CRL, orig_lig, h_lig,
        wsb + WTN1L, nl_b1, wsb + WTN2L, nl_b2, out + O_HL);
    node_mfma<<<N_REC / 32, 256, 0, stream>>>(
        wsf + AGGRR, wsf + CNTR, wsb + CRR, orig_rec, h_rec,
        wsb + WTN1R, nr_b1, wsb + WTN2R, nr_b2, out + O_HR);

    (void)in_sizes; (void)n_in; (void)out_size; (void)ws_size;
}

// Round 6
// 1591.962 us; speedup vs baseline: 12.7079x; 1.3960x over previous
//
#include <hip/hip_runtime.h>
#include <hip/hip_bf16.h>

// ---------------------------------------------------------------------------
// IEGMN layer, MI355X round-6: swizzled-weight MFMA GEMMs + reg double-buffer.
//   zero_kernel  : zero atomic accumulators
//   wt_swz       : pack weights fp32[K][256] -> bf16 fragment-ordered blobs
//   edge_mfma    : gather + RBF + edge MLP + coords MLP + atomic seg-sums
//   proj_mfma    : q/k/v projections -> bf16 ws (MFMA)
//   attn_mfma    : flash attention partial (split-K), MFMA 16x16x32 bf16
//   attn_combine : merge splits -> bf16 cross features
//   coords_fin   : x_ev -> out (fp32)
//   node_mfma    : node MLP + skip -> out (fp32, MFMA)
// ---------------------------------------------------------------------------

#define N_LIG   4096
#define N_REC   16384
#define E_LIG_N 65536
#define E_REC_N 262144
#define HD      256
#define ORIGD   64
#define EFD     16
#define NSIG    15
#define EIN     543      // 2*HD + EFD + NSIG
#define XP      552      // edge sX pitch (bf16 elems), 544 used
#define XPN     584      // node sX pitch, 576 used
#define XPP     264      // proj sX pitch, 256 used

typedef __bf16 bf16x8 __attribute__((ext_vector_type(8)));
typedef float  f32x4  __attribute__((ext_vector_type(4)));

__device__ __forceinline__ float lrelu(float x) { return x > 0.f ? x : 0.01f * x; }
__device__ __forceinline__ unsigned short f2bu(float f) {
    __hip_bfloat16 h = __float2bfloat16(f);
    return *reinterpret_cast<unsigned short*>(&h);
}

// ---------------------------------------------------------------------------
// Shared 32xKx256 GEMM core. A: LDS rows 0..31 (bf16, given pitch).
// Wswz: fragment-ordered weights, this wave's group base. KS = K/32.
// acc[mt][nt] over rows mt*16+quad*4+r, cols wave*64+nt*16+col.
__device__ __forceinline__ void mfma_gemm(
    const unsigned short* sA, int pitch,
    const __hip_bfloat16* Wswz, int KS, int lane, f32x4 acc[2][4])
{
    const int col = lane & 15, quad = lane >> 4;
    const unsigned short* a0p = sA + (size_t)col * pitch + quad * 8;
    const unsigned short* a1p = sA + (size_t)(16 + col) * pitch + quad * 8;
    const __hip_bfloat16* wp = Wswz + lane * 8;
    bf16x8 bc[4], bn[4], a0c, a1c, a0n, a1n;
    #pragma unroll
    for (int nt = 0; nt < 4; ++nt)
        bc[nt] = *reinterpret_cast<const bf16x8*>(wp + (size_t)nt * KS * 512);
    a0c = *reinterpret_cast<const bf16x8*>(a0p);
    a1c = *reinterpret_cast<const bf16x8*>(a1p);
    for (int ks = 0; ks < KS; ++ks) {
        if (ks + 1 < KS) {
            #pragma unroll
            for (int nt = 0; nt < 4; ++nt)
                bn[nt] = *reinterpret_cast<const bf16x8*>(
                    wp + ((size_t)nt * KS + ks + 1) * 512);
            a0n = *reinterpret_cast<const bf16x8*>(a0p + (ks + 1) * 32);
            a1n = *reinterpret_cast<const bf16x8*>(a1p + (ks + 1) * 32);
        }
        #pragma unroll
        for (int nt = 0; nt < 4; ++nt) {
            acc[0][nt] = __builtin_amdgcn_mfma_f32_16x16x32_bf16(a0c, bc[nt], acc[0][nt], 0, 0, 0);
            acc[1][nt] = __builtin_amdgcn_mfma_f32_16x16x32_bf16(a1c, bc[nt], acc[1][nt], 0, 0, 0);
        }
        #pragma unroll
        for (int nt = 0; nt < 4; ++nt) bc[nt] = bn[nt];
        a0c = a0n; a1c = a1n;
    }
}

// ---------------------------------------------------------------------------
__global__ void zero_kernel(float* __restrict__ p, int n) {
    int i = blockIdx.x * 256 + threadIdx.x;
    if (i < n) p[i] = 0.f;
}

// ---------------------------------------------------------------------------
// Fragment-order weight pack: src fp32 [K][256] -> dst[(g*KS+ks)*64+lane][8],
// element j of lane = W[k = ks*32 + (lane>>4)*8 + j][n = g*16 + (lane&15)].
__global__ void wt_swz(const float* __restrict__ src,
                       __hip_bfloat16* __restrict__ dst, int K, int KS) {
    const int g  = blockIdx.x / KS;
    const int ks = blockIdx.x % KS;
    for (int i = threadIdx.x; i < 512; i += 256) {
        const int lane = i >> 3, j = i & 7;
        const int n = g * 16 + (lane & 15);
        const int k = ks * 32 + (lane >> 4) * 8 + j;
        const float v = (k < K) ? src[(size_t)k * 256 + n] : 0.f;
        dst[((size_t)(g * KS + ks) * 64 + lane) * 8 + j] = __float2bfloat16(v);
    }
}

// ---------------------------------------------------------------------------
// Edge MFMA kernel: 32 edges/block, 256 threads (4 waves x 64-col strips).
__global__ __launch_bounds__(256, 4) void edge_mfma(
    const float* __restrict__ coords, const float* __restrict__ h,
    const float* __restrict__ ef,
    const int* __restrict__ src, const int* __restrict__ dst,
    const __hip_bfloat16* __restrict__ W1s, const float* __restrict__ b1,
    const __hip_bfloat16* __restrict__ W2s, const float* __restrict__ b2,
    const __hip_bfloat16* __restrict__ Wc1s, const float* __restrict__ bc1,
    const float* __restrict__ wc2v, const float* __restrict__ bc2,
    float* __restrict__ aggr, float* __restrict__ cnt, float* __restrict__ xsum)
{
    __shared__ unsigned short sX[32][XP];   // input 544 -> hid 256 -> msg 256
    __shared__ float sXrel[32][3];
    __shared__ int   sDst[32];
    __shared__ float sRedW[4][32];

    const int tid  = threadIdx.x;
    const int lane = tid & 63;
    const int wave = tid >> 6;
    const int col  = lane & 15;
    const int quad = lane >> 4;
    const int e0   = blockIdx.x * 32;

    // ---- gather h_src | h_dst (cols 0..511) ----
    for (int i = tid; i < 32 * 128; i += 256) {
        const int row = i >> 7, c4 = i & 127;
        const int node = (c4 < 64) ? src[e0 + row] : dst[e0 + row];
        const float4 v = *reinterpret_cast<const float4*>(
            &h[(size_t)node * HD + (c4 & 63) * 4]);
        ushort4 u = { f2bu(v.x), f2bu(v.y), f2bu(v.z), f2bu(v.w) };
        *reinterpret_cast<ushort4*>(&sX[row][c4 * 4]) = u;
    }
    // ---- ef (cols 512..527) ----
    if (tid < 128) {
        const int row = tid >> 2, c = tid & 3;
        const float4 v = *reinterpret_cast<const float4*>(
            &ef[(size_t)(e0 + row) * EFD + c * 4]);
        ushort4 u = { f2bu(v.x), f2bu(v.y), f2bu(v.z), f2bu(v.w) };
        *reinterpret_cast<ushort4*>(&sX[row][512 + c * 4]) = u;
    }
    // ---- rbf (cols 528..542), pad 543, xrel, dst ----
    if (tid < 32) {
        const int e = e0 + tid;
        const int s = src[e], d = dst[e];
        sDst[tid] = d;
        float d2 = 0.f;
        #pragma unroll
        for (int c = 0; c < 3; ++c) {
            const float xr = coords[s * 3 + c] - coords[d * 3 + c];
            sXrel[tid][c] = xr;
            d2 += xr * xr;
        }
        float sig = 1.0f;
        #pragma unroll
        for (int si = 0; si < NSIG; ++si) {
            sX[tid][528 + si] = f2bu(__expf(-d2 / sig));
            sig *= 1.5f;
        }
        sX[tid][543] = 0;
    }
    __syncthreads();

    f32x4 acc[2][4];

    // ---- layer 1: 544 -> 256 ----
    #pragma unroll
    for (int nt = 0; nt < 4; ++nt) {
        const float bv = b1[wave * 64 + nt * 16 + col];
        acc[0][nt] = { bv, bv, bv, bv };
        acc[1][nt] = { bv, bv, bv, bv };
    }
    mfma_gemm(&sX[0][0], XP, W1s + (size_t)(wave * 4) * 17 * 512, 17, lane, acc);
    __syncthreads();                         // everyone done reading input
    #pragma unroll
    for (int mt = 0; mt < 2; ++mt)
        #pragma unroll
        for (int nt = 0; nt < 4; ++nt)
            #pragma unroll
            for (int r = 0; r < 4; ++r)
                sX[mt * 16 + quad * 4 + r][wave * 64 + nt * 16 + col] =
                    f2bu(lrelu(acc[mt][nt][r]));
    __syncthreads();

    // ---- layer 2: 256 -> 256 (msg) ----
    #pragma unroll
    for (int nt = 0; nt < 4; ++nt) {
        const float bv = b2[wave * 64 + nt * 16 + col];
        acc[0][nt] = { bv, bv, bv, bv };
        acc[1][nt] = { bv, bv, bv, bv };
    }
    mfma_gemm(&sX[0][0], XP, W2s + (size_t)(wave * 4) * 8 * 512, 8, lane, acc);
    __syncthreads();                         // everyone done reading hid
    #pragma unroll
    for (int mt = 0; mt < 2; ++mt)
        #pragma unroll
        for (int nt = 0; nt < 4; ++nt)
            #pragma unroll
            for (int r = 0; r < 4; ++r) {
                const int row = mt * 16 + quad * 4 + r;
                const int n   = wave * 64 + nt * 16 + col;
                const float v = acc[mt][nt][r];
                atomicAdd(&aggr[(size_t)sDst[row] * HD + n], v);
                sX[row][n] = f2bu(v);
            }
    __syncthreads();

    // ---- coords MLP: 256 -> 256 (lrelu) -> dot wc2 ----
    #pragma unroll
    for (int nt = 0; nt < 4; ++nt) {
        const float bv = bc1[wave * 64 + nt * 16 + col];
        acc[0][nt] = { bv, bv, bv, bv };
        acc[1][nt] = { bv, bv, bv, bv };
    }
    mfma_gemm(&sX[0][0], XP, Wc1s + (size_t)(wave * 4) * 8 * 512, 8, lane, acc);
    float w2l[4];
    #pragma unroll
    for (int nt = 0; nt < 4; ++nt) w2l[nt] = wc2v[wave * 64 + nt * 16 + col];
    #pragma unroll
    for (int mt = 0; mt < 2; ++mt) {
        float pr[4] = { 0.f, 0.f, 0.f, 0.f };
        #pragma unroll
        for (int nt = 0; nt < 4; ++nt)
            #pragma unroll
            for (int r = 0; r < 4; ++r)
                pr[r] += lrelu(acc[mt][nt][r]) * w2l[nt];
        #pragma unroll
        for (int r = 0; r < 4; ++r) {
            #pragma unroll
            for (int off = 1; off < 16; off <<= 1) pr[r] += __shfl_xor(pr[r], off);
        }
        if (col == 0)
            #pragma unroll
            for (int r = 0; r < 4; ++r)
                sRedW[wave][mt * 16 + quad * 4 + r] = pr[r];
    }
    __syncthreads();
    if (tid < 32) {
        const float p = sRedW[0][tid] + sRedW[1][tid] + sRedW[2][tid] + sRedW[3][tid] + bc2[0];
        const int d = sDst[tid];
        #pragma unroll
        for (int c = 0; c < 3; ++c)
            atomicAdd(&xsum[(size_t)d * 3 + c], sXrel[tid][c] * p);
        atomicAdd(&cnt[d], 1.0f);
    }
}

// ---------------------------------------------------------------------------
// Node MFMA kernel: 32 nodes/block. [aggr_mean|cross|orig] 576 -> 256 -> 256.
__global__ __launch_bounds__(256, 4) void node_mfma(
    const float* __restrict__ aggr, const float* __restrict__ cnt,
    const __hip_bfloat16* __restrict__ cross, const float* __restrict__ orig,
    const float* __restrict__ hfeat,
    const __hip_bfloat16* __restrict__ WN1s, const float* __restrict__ b1,
    const __hip_bfloat16* __restrict__ WN2s, const float* __restrict__ b2,
    float* __restrict__ out)
{
    __shared__ unsigned short sXn[32][XPN];
    __shared__ float sInv[32];

    const int tid  = threadIdx.x;
    const int lane = tid & 63;
    const int wave = tid >> 6;
    const int col  = lane & 15;
    const int quad = lane >> 4;
    const int r0   = blockIdx.x * 32;

    if (tid < 32) sInv[tid] = 1.f / fmaxf(cnt[r0 + tid], 1.f);
    __syncthreads();

    for (int i = tid; i < 32 * 64; i += 256) {
        const int row = i >> 6, c4 = i & 63;
        const float inv = sInv[row];
        const float4 v = *reinterpret_cast<const float4*>(
            &aggr[(size_t)(r0 + row) * HD + c4 * 4]);
        ushort4 u = { f2bu(v.x * inv), f2bu(v.y * inv), f2bu(v.z * inv), f2bu(v.w * inv) };
        *reinterpret_cast<ushort4*>(&sXn[row][c4 * 4]) = u;
    }
    for (int i = tid; i < 32 * 64; i += 256) {
        const int row = i >> 6, c4 = i & 63;
        const ushort4 u = *reinterpret_cast<const ushort4*>(
            &cross[(size_t)(r0 + row) * HD + c4 * 4]);
        *reinterpret_cast<ushort4*>(&sXn[row][256 + c4 * 4]) = u;
    }
    for (int i = tid; i < 32 * 16; i += 256) {
        const int row = i >> 4, c4 = i & 15;
        const float4 v = *reinterpret_cast<const float4*>(
            &orig[(size_t)(r0 + row) * ORIGD + c4 * 4]);
        ushort4 u = { f2bu(v.x), f2bu(v.y), f2bu(v.z), f2bu(v.w) };
        *reinterpret_cast<ushort4*>(&sXn[row][512 + c4 * 4]) = u;
    }
    __syncthreads();

    f32x4 acc[2][4];

    // layer 1: 576 -> 256
    #pragma unroll
    for (int nt = 0; nt < 4; ++nt) {
        const float bv = b1[wave * 64 + nt * 16 + col];
        acc[0][nt] = { bv, bv, bv, bv };
        acc[1][nt] = { bv, bv, bv, bv };
    }
    mfma_gemm(&sXn[0][0], XPN, WN1s + (size_t)(wave * 4) * 18 * 512, 18, lane, acc);
    __syncthreads();
    #pragma unroll
    for (int mt = 0; mt < 2; ++mt)
        #pragma unroll
        for (int nt = 0; nt < 4; ++nt)
            #pragma unroll
            for (int r = 0; r < 4; ++r)
                sXn[mt * 16 + quad * 4 + r][wave * 64 + nt * 16 + col] =
                    f2bu(lrelu(acc[mt][nt][r]));
    __syncthreads();

    // layer 2: 256 -> 256, skip
    #pragma unroll
    for (int nt = 0; nt < 4; ++nt) {
        const float bv = b2[wave * 64 + nt * 16 + col];
        acc[0][nt] = { bv, bv, bv, bv };
        acc[1][nt] = { bv, bv, bv, bv };
    }
    mfma_gemm(&sXn[0][0], XPN, WN2s + (size_t)(wave * 4) * 8 * 512, 8, lane, acc);
    #pragma unroll
    for (int mt = 0; mt < 2; ++mt)
        #pragma unroll
        for (int nt = 0; nt < 4; ++nt)
            #pragma unroll
            for (int r = 0; r < 4; ++r) {
                const int g = r0 + mt * 16 + quad * 4 + r;
                const int n = wave * 64 + nt * 16 + col;
                out[(size_t)g * HD + n] =
                    0.5f * acc[mt][nt][r] + 0.5f * hfeat[(size_t)g * HD + n];
            }
}

// ---------------------------------------------------------------------------
// Projection MFMA: out[N,256] = (lrelu?)(X @ W) -> bf16. 32 rows/block.
__global__ __launch_bounds__(256, 4) void proj_mfma(
    const float* __restrict__ X, const __hip_bfloat16* __restrict__ Ws,
    __hip_bfloat16* __restrict__ out, int applyLrelu)
{
    __shared__ unsigned short sXp[32][XPP];
    const int tid  = threadIdx.x;
    const int lane = tid & 63;
    const int wave = tid >> 6;
    const int col  = lane & 15;
    const int quad = lane >> 4;
    const int r0   = blockIdx.x * 32;

    for (int i = tid; i < 32 * 64; i += 256) {
        const int row = i >> 6, c4 = i & 63;
        const float4 v = *reinterpret_cast<const float4*>(
            &X[(size_t)(r0 + row) * HD + c4 * 4]);
        ushort4 u = { f2bu(v.x), f2bu(v.y), f2bu(v.z), f2bu(v.w) };
        *reinterpret_cast<ushort4*>(&sXp[row][c4 * 4]) = u;
    }
    __syncthreads();

    f32x4 acc[2][4];
    #pragma unroll
    for (int nt = 0; nt < 4; ++nt) {
        acc[0][nt] = { 0.f, 0.f, 0.f, 0.f };
        acc[1][nt] = { 0.f, 0.f, 0.f, 0.f };
    }
    mfma_gemm(&sXp[0][0], XPP, Ws + (size_t)(wave * 4) * 8 * 512, 8, lane, acc);
    #pragma unroll
    for (int mt = 0; mt < 2; ++mt)
        #pragma unroll
        for (int nt = 0; nt < 4; ++nt)
            #pragma unroll
            for (int r = 0; r < 4; ++r) {
                float v = acc[mt][nt][r];
                if (applyLrelu) v = lrelu(v);
                out[(size_t)(r0 + mt * 16 + quad * 4 + r) * HD +
                    wave * 64 + nt * 16 + col] = __float2bfloat16(v);
            }
}

// ---------------------------------------------------------------------------
// MFMA flash attention partial. 64 q-rows/block (4 waves x 16), 32-key tiles.
__global__ __launch_bounds__(256, 2) void attn_mfma(
    const __hip_bfloat16* __restrict__ Qb, const __hip_bfloat16* __restrict__ Kb,
    const __hip_bfloat16* __restrict__ Vb, const float* __restrict__ maskG,
    float* __restrict__ PO, float* __restrict__ PM, float* __restrict__ PL,
    int M, int chunkKeys, int transposed)
{
    __shared__ unsigned short sK[32][264];
    __shared__ unsigned short sVt[256][40];
    __shared__ unsigned short sP[4][16][40];
    __shared__ float          sMask[64][36];

    const int tid  = threadIdx.x;
    const int lane = tid & 63;
    const int wave = tid >> 6;
    const int col  = lane & 15;
    const int quad = lane >> 4;
    const int R0   = blockIdx.x * 64;
    const int split = blockIdx.y;
    const int jbase = split * chunkKeys;

    bf16x8 qf[8];
    {
        const __hip_bfloat16* qp =
            Qb + (size_t)(R0 + wave * 16 + col) * HD + quad * 8;
        #pragma unroll
        for (int s = 0; s < 8; ++s)
            qf[s] = *reinterpret_cast<const bf16x8*>(qp + 32 * s);
    }

    f32x4 o[16];
    #pragma unroll
    for (int dt = 0; dt < 16; ++dt) { o[dt][0]=0.f; o[dt][1]=0.f; o[dt][2]=0.f; o[dt][3]=0.f; }
    float m[4], l[4];
    #pragma unroll
    for (int r = 0; r < 4; ++r) { m[r] = -INFINITY; l[r] = 0.f; }

    for (int jt = 0; jt < chunkKeys; jt += 32) {
        const int j0 = jbase + jt;
        __syncthreads();
        {
            const int key = tid >> 3;
            const int d0  = (tid & 7) * 32;
            const __hip_bfloat16* kp = Kb + (size_t)(j0 + key) * HD + d0;
            #pragma unroll
            for (int i = 0; i < 4; ++i)
                *reinterpret_cast<uint4*>(&sK[key][d0 + 8 * i]) =
                    *reinterpret_cast<const uint4*>(kp + 8 * i);
        }
        {
            const int key = tid & 31;
            const int d0  = (tid >> 5) * 32;
            const __hip_bfloat16* vp = Vb + (size_t)(j0 + key) * HD + d0;
            #pragma unroll
            for (int i = 0; i < 4; ++i) {
                unsigned short tmp[8];
                *reinterpret_cast<uint4*>(tmp) = *reinterpret_cast<const uint4*>(vp + 8 * i);
                #pragma unroll
                for (int u = 0; u < 8; ++u)
                    sVt[d0 + 8 * i + u][key] = tmp[u];
            }
        }
        if (!transposed) {
            const int row = tid >> 2;
            const int c0  = (tid & 3) * 8;
            #pragma unroll
            for (int i = 0; i < 2; ++i)
                *reinterpret_cast<float4*>(&sMask[row][c0 + 4 * i]) =
                    *reinterpret_cast<const float4*>(
                        &maskG[(size_t)(R0 + row) * N_REC + j0 + c0 + 4 * i]);
        } else {
            const int key = tid >> 3;
            const int r0m = (tid & 7) * 8;
            #pragma unroll
            for (int i = 0; i < 2; ++i) {
                float tmp[4];
                *reinterpret_cast<float4*>(tmp) =
                    *reinterpret_cast<const float4*>(
                        &maskG[(size_t)(j0 + key) * N_REC + R0 + r0m + 4 * i]);
                #pragma unroll
                for (int u = 0; u < 4; ++u)
                    sMask[r0m + 4 * i + u][key] = tmp[u];
            }
        }
        __syncthreads();

        f32x4 sacc[2];
        sacc[0][0]=0.f; sacc[0][1]=0.f; sacc[0][2]=0.f; sacc[0][3]=0.f;
        sacc[1][0]=0.f; sacc[1][1]=0.f; sacc[1][2]=0.f; sacc[1][3]=0.f;
        #pragma unroll
        for (int t = 0; t < 2; ++t) {
            #pragma unroll
            for (int s = 0; s < 8; ++s) {
                bf16x8 kf = *reinterpret_cast<const bf16x8*>(
                    &sK[col + 16 * t][32 * s + quad * 8]);
                sacc[t] = __builtin_amdgcn_mfma_f32_16x16x32_bf16(qf[s], kf, sacc[t], 0, 0, 0);
            }
        }

        float a[2][4];
        #pragma unroll
        for (int t = 0; t < 2; ++t)
            #pragma unroll
            for (int r = 0; r < 4; ++r) {
                const float mv = sMask[wave * 16 + quad * 4 + r][col + 16 * t];
                a[t][r] = mv * sacc[t][r] - 1000.f * (1.f - mv);
            }
        #pragma unroll
        for (int r = 0; r < 4; ++r) {
            float mx = fmaxf(a[0][r], a[1][r]);
            #pragma unroll
            for (int off = 1; off < 16; off <<= 1)
                mx = fmaxf(mx, __shfl_xor(mx, off));
            const float mn = fmaxf(m[r], mx);
            const float c  = __expf(m[r] - mn);
            m[r] = mn;
            const float p0 = __expf(a[0][r] - mn);
            const float p1 = __expf(a[1][r] - mn);
            sP[wave][quad * 4 + r][col]      = f2bu(p0);
            sP[wave][quad * 4 + r][col + 16] = f2bu(p1);
            float ps = p0 + p1;
            #pragma unroll
            for (int off = 1; off < 16; off <<= 1)
                ps += __shfl_xor(ps, off);
            l[r] = l[r] * c + ps;
            #pragma unroll
            for (int dt = 0; dt < 16; ++dt) o[dt][r] *= c;
        }

        bf16x8 pf = *reinterpret_cast<const bf16x8*>(&sP[wave][col][quad * 8]);
        #pragma unroll
        for (int dt = 0; dt < 16; ++dt) {
            bf16x8 vf = *reinterpret_cast<const bf16x8*>(
                &sVt[col + 16 * dt][quad * 8]);
            o[dt] = __builtin_amdgcn_mfma_f32_16x16x32_bf16(pf, vf, o[dt], 0, 0, 0);
        }
    }

    #pragma unroll
    for (int dt = 0; dt < 16; ++dt)
        #pragma unroll
        for (int r = 0; r < 4; ++r) {
            const int row = R0 + wave * 16 + quad * 4 + r;
            PO[((size_t)split * M + row) * HD + dt * 16 + col] = o[dt][r];
        }
    if (col == 0) {
        #pragma unroll
        for (int r = 0; r < 4; ++r) {
            const int row = R0 + wave * 16 + quad * 4 + r;
            PM[(size_t)split * M + row] = m[r];
            PL[(size_t)split * M + row] = l[r];
        }
    }
}

// ---------------------------------------------------------------------------
__global__ void attn_combine(
    const float* __restrict__ PO, const float* __restrict__ PM,
    const float* __restrict__ PL, __hip_bfloat16* __restrict__ Out,
    int M, int nchunks)
{
    const int idx = blockIdx.x * 256 + threadIdx.x;
    const int row = idx >> 8;
    float mmax = -INFINITY;
    for (int c = 0; c < nchunks; ++c) mmax = fmaxf(mmax, PM[(size_t)c * M + row]);
    float denom = 0.f, acc = 0.f;
    for (int c = 0; c < nchunks; ++c) {
        const float w = __expf(PM[(size_t)c * M + row] - mmax);
        denom += PL[(size_t)c * M + row] * w;
        acc   += PO[(size_t)c * M * HD + idx] * w;
    }
    Out[idx] = __float2bfloat16(acc / denom);
}

// ---------------------------------------------------------------------------
__global__ void coords_fin(
    const float* __restrict__ coords, const float* __restrict__ origc,
    const float* __restrict__ xsum, const float* __restrict__ cnt,
    float* __restrict__ out, int n)
{
    const int i = blockIdx.x * 256 + threadIdx.x;
    if (i >= n * 3) return;
    const int node = i / 3;
    const float inv = 1.f / fmaxf(cnt[node], 1.f);
    out[i] = 0.25f * origc[i] + 0.75f * coords[i] + xsum[i] * inv;
}

// ---------------------------------------------------------------------------
extern "C" void kernel_launch(void* const* d_in, const int* in_sizes, int n_in,
                              void* d_out, int out_size, void* d_ws, size_t ws_size,
                              hipStream_t stream)
{
    const float* coords_lig = (const float*)d_in[0];
    const float* h_lig      = (const float*)d_in[1];
    const float* orig_lig   = (const float*)d_in[2];
    const float* origc_lig  = (const float*)d_in[3];
    const float* coords_rec = (const float*)d_in[4];
    const float* h_rec      = (const float*)d_in[5];
    const float* orig_rec   = (const float*)d_in[6];
    const float* origc_rec  = (const float*)d_in[7];
    const float* mask       = (const float*)d_in[8];
    const float* lig_ef     = (const float*)d_in[9];
    const float* rec_ef     = (const float*)d_in[10];
    const int* lig_src = (const int*)d_in[11];
    const int* lig_dst = (const int*)d_in[12];
    const int* rec_src = (const int*)d_in[13];
    const int* rec_dst = (const int*)d_in[14];
    const float* le_w1 = (const float*)d_in[15];
    const float* le_b1 = (const float*)d_in[16];
    const float* le_w2 = (const float*)d_in[17];
    const float* le_b2 = (const float*)d_in[18];
    const float* re_w1 = (const float*)d_in[19];
    const float* re_b1 = (const float*)d_in[20];
    const float* re_w2 = (const float*)d_in[21];
    const float* re_b2 = (const float*)d_in[22];
    const float* aql_w = (const float*)d_in[23];
    const float* akl_w = (const float*)d_in[24];
    const float* avl_w = (const float*)d_in[25];
    const float* aqr_w = (const float*)d_in[26];
    const float* akr_w = (const float*)d_in[27];
    const float* avr_w = (const float*)d_in[28];
    const float* nl_w1 = (const float*)d_in[29];
    const float* nl_b1 = (const float*)d_in[30];
    const float* nl_w2 = (const float*)d_in[31];
    const float* nl_b2 = (const float*)d_in[32];
    const float* nr_w1 = (const float*)d_in[33];
    const float* nr_b1 = (const float*)d_in[34];
    const float* nr_w2 = (const float*)d_in[35];
    const float* nr_b2 = (const float*)d_in[36];
    const float* cl_w1 = (const float*)d_in[37];
    const float* cl_b1 = (const float*)d_in[38];
    const float* cl_w2 = (const float*)d_in[39];
    const float* cl_b2 = (const float*)d_in[40];
    const float* cr_w1 = (const float*)d_in[41];
    const float* cr_b1 = (const float*)d_in[42];
    const float* cr_w2 = (const float*)d_in[43];
    const float* cr_b2 = (const float*)d_in[44];

    float* out = (float*)d_out;
    float* wsf = (float*)d_ws;

    // ---- fp32 zone ----
    const size_t AGGRL = 0;
    const size_t AGGRR = AGGRL + (size_t)N_LIG * HD;
    const size_t CNTL  = AGGRR + (size_t)N_REC * HD;
    const size_t CNTR  = CNTL + N_LIG;
    const size_t XSUML = CNTR + N_REC;
    const size_t XSUMR = XSUML + (size_t)N_LIG * 3;
    const size_t ZEND  = XSUMR + (size_t)N_REC * 3;          // zeroed region
    const size_t PO_   = ZEND;                               // 8*N_LIG*HD == 2*N_REC*HD
    const size_t PM_   = PO_ + (size_t)8 * N_LIG * HD;
    const size_t PL_   = PM_ + (size_t)8 * N_LIG;
    const size_t FEND  = PL_ + (size_t)8 * N_LIG;

    // ---- bf16 zone ----
    __hip_bfloat16* wsb = (__hip_bfloat16*)(wsf + FEND);
    const size_t QL  = 0;
    const size_t KL  = QL + (size_t)N_LIG * HD;
    const size_t VL  = KL + (size_t)N_LIG * HD;
    const size_t QR  = VL + (size_t)N_LIG * HD;
    const size_t KR  = QR + (size_t)N_REC * HD;
    const size_t VR  = KR + (size_t)N_REC * HD;
    const size_t CRL = VR + (size_t)N_REC * HD;
    const size_t CRR = CRL + (size_t)N_LIG * HD;
    // swizzled weights (bf16 elems)
    const size_t EW1SZ = (size_t)16 * 17 * 512;   // 139264
    const size_t KW256 = (size_t)16 * 8 * 512;    // 65536
    const size_t NW1SZ = (size_t)16 * 18 * 512;   // 147456
    const size_t SW_EL1 = CRR + (size_t)N_REC * HD;
    const size_t SW_EL2 = SW_EL1 + EW1SZ;
    const size_t SW_EC1 = SW_EL2 + KW256;
    const size_t SW_NL1 = SW_EC1 + KW256;
    const size_t SW_NL2 = SW_NL1 + NW1SZ;
    const size_t SW_ER1 = SW_NL2 + KW256;
    const size_t SW_ER2 = SW_ER1 + EW1SZ;
    const size_t SW_EC1R = SW_ER2 + KW256;
    const size_t SW_NR1 = SW_EC1R + KW256;
    const size_t SW_NR2 = SW_NR1 + NW1SZ;
    const size_t SW_PQL = SW_NR2 + KW256;
    const size_t SW_PKL = SW_PQL + KW256;
    const size_t SW_PVL = SW_PKL + KW256;
    const size_t SW_PQR = SW_PVL + KW256;
    const size_t SW_PKR = SW_PQR + KW256;
    const size_t SW_PVR = SW_PKR + KW256;

    const size_t O_XL = 0;
    const size_t O_HL = O_XL + (size_t)N_LIG * 3;
    const size_t O_XR = O_HL + (size_t)N_LIG * HD;
    const size_t O_HR = O_XR + (size_t)N_REC * 3;

    // 1) zero atomic accumulators
    zero_kernel<<<((int)ZEND + 255) / 256, 256, 0, stream>>>(wsf, (int)ZEND);

    // 2) weight swizzles
    wt_swz<<<16 * 17, 256, 0, stream>>>(le_w1, wsb + SW_EL1, EIN, 17);
    wt_swz<<<16 * 8,  256, 0, stream>>>(le_w2, wsb + SW_EL2, 256, 8);
    wt_swz<<<16 * 8,  256, 0, stream>>>(cl_w1, wsb + SW_EC1, 256, 8);
    wt_swz<<<16 * 18, 256, 0, stream>>>(nl_w1, wsb + SW_NL1, 576, 18);
    wt_swz<<<16 * 8,  256, 0, stream>>>(nl_w2, wsb + SW_NL2, 256, 8);
    wt_swz<<<16 * 17, 256, 0, stream>>>(re_w1, wsb + SW_ER1, EIN, 17);
    wt_swz<<<16 * 8,  256, 0, stream>>>(re_w2, wsb + SW_ER2, 256, 8);
    wt_swz<<<16 * 8,  256, 0, stream>>>(cr_w1, wsb + SW_EC1R, 256, 8);
    wt_swz<<<16 * 18, 256, 0, stream>>>(nr_w1, wsb + SW_NR1, 576, 18);
    wt_swz<<<16 * 8,  256, 0, stream>>>(nr_w2, wsb + SW_NR2, 256, 8);
    wt_swz<<<16 * 8,  256, 0, stream>>>(aql_w, wsb + SW_PQL, 256, 8);
    wt_swz<<<16 * 8,  256, 0, stream>>>(akl_w, wsb + SW_PKL, 256, 8);
    wt_swz<<<16 * 8,  256, 0, stream>>>(avl_w, wsb + SW_PVL, 256, 8);
    wt_swz<<<16 * 8,  256, 0, stream>>>(aqr_w, wsb + SW_PQR, 256, 8);
    wt_swz<<<16 * 8,  256, 0, stream>>>(akr_w, wsb + SW_PKR, 256, 8);
    wt_swz<<<16 * 8,  256, 0, stream>>>(avr_w, wsb + SW_PVR, 256, 8);

    // 3) edge MFMA kernels
    edge_mfma<<<E_LIG_N / 32, 256, 0, stream>>>(
        coords_lig, h_lig, lig_ef, lig_src, lig_dst,
        wsb + SW_EL1, le_b1, wsb + SW_EL2, le_b2, wsb + SW_EC1, cl_b1, cl_w2, cl_b2,
        wsf + AGGRL, wsf + CNTL, wsf + XSUML);
    edge_mfma<<<E_REC_N / 32, 256, 0, stream>>>(
        coords_rec, h_rec, rec_ef, rec_src, rec_dst,
        wsb + SW_ER1, re_b1, wsb + SW_ER2, re_b2, wsb + SW_EC1R, cr_b1, cr_w2, cr_b2,
        wsf + AGGRR, wsf + CNTR, wsf + XSUMR);

    // 4) projections -> bf16 (MFMA)
    proj_mfma<<<N_LIG / 32, 256, 0, stream>>>(h_lig, wsb + SW_PQL, wsb + QL, 1);
    proj_mfma<<<N_LIG / 32, 256, 0, stream>>>(h_lig, wsb + SW_PKL, wsb + KL, 1);
    proj_mfma<<<N_LIG / 32, 256, 0, stream>>>(h_lig, wsb + SW_PVL, wsb + VL, 0);
    proj_mfma<<<N_REC / 32, 256, 0, stream>>>(h_rec, wsb + SW_PQR, wsb + QR, 1);
    proj_mfma<<<N_REC / 32, 256, 0, stream>>>(h_rec, wsb + SW_PKR, wsb + KR, 1);
    proj_mfma<<<N_REC / 32, 256, 0, stream>>>(h_rec, wsb + SW_PVR, wsb + VR, 0);

    // 5) MFMA flash attention, split-K + combine
    {
        dim3 gl(N_LIG / 64, 8);
        attn_mfma<<<gl, 256, 0, stream>>>(wsb + QL, wsb + KR, wsb + VR, mask,
                                          wsf + PO_, wsf + PM_, wsf + PL_,
                                          N_LIG, N_REC / 8, 0);
        attn_combine<<<N_LIG, 256, 0, stream>>>(
            wsf + PO_, wsf + PM_, wsf + PL_, wsb + CRL, N_LIG, 8);

        dim3 gr(N_REC / 64, 2);
        attn_mfma<<<gr, 256, 0, stream>>>(wsb + QR, wsb + KL, wsb + VL, mask,
                                          wsf + PO_, wsf + PM_, wsf + PL_,
                                          N_REC, N_LIG / 2, 1);
        attn_combine<<<N_REC, 256, 0, stream>>>(
            wsf + PO_, wsf + PM_, wsf + PL_, wsb + CRR, N_REC, 2);
    }

    // 6) coordinate outputs
    coords_fin<<<(N_LIG * 3 + 255) / 256, 256, 0, stream>>>(
        coords_lig, origc_lig, wsf + XSUML, wsf + CNTL, out + O_XL, N_LIG);
    coords_fin<<<(N_REC * 3 + 255) / 256, 256, 0, stream>>>(
        coords_rec, origc_rec, wsf + XSUMR, wsf + CNTR, out + O_XR, N_REC);

    // 7) node MFMA kernels
    node_mfma<<<N_LIG / 32, 256, 0, stream>>>(
        wsf + AGGRL, wsf + CNTL, wsb + CRL, orig_lig, h_lig,
        wsb + SW_NL1, nl_b1, wsb + SW_NL2, nl_b2, out + O_HL);
    node_mfma<<<N_REC / 32, 256, 0, stream>>>(
        wsf + AGGRR, wsf + CNTR, wsb + CRR, orig_rec, h_rec,
        wsb + SW_NR1, nr_b1, wsb + SW_NR2, nr_b2, out + O_HR);

    (void)in_sizes; (void)n_in; (void)out_size; (void)ws_size;
}

// Round 7
// 1583.504 us; speedup vs baseline: 12.7758x; 1.0053x over previous
//
#include <hip/hip_runtime.h>
#include <hip/hip_bf16.h>

// ---------------------------------------------------------------------------
// IEGMN layer, MI355X round-7: attention V^T precompute + more split-K.
//   zero_kernel  : zero atomic accumulators
//   wt_swz       : pack weights fp32[K][256] -> bf16 fragment-ordered blobs
//   edge_mfma    : gather + RBF + edge MLP + coords MLP + atomic seg-sums
//   proj_mfma    : q/k/v projections -> bf16 ws (MFMA)
//   vt_kernel    : V [N][256] -> V^T [256][N] (bf16, LDS-tiled)
//   attn_mfma    : flash attention partial (split-K), MFMA 16x16x32 bf16
//   attn_combine : merge splits -> bf16 cross features
//   coords_fin   : x_ev -> out (fp32)
//   node_mfma    : node MLP + skip -> out (fp32, MFMA)
// ---------------------------------------------------------------------------

#define N_LIG   4096
#define N_REC   16384
#define E_LIG_N 65536
#define E_REC_N 262144
#define HD      256
#define ORIGD   64
#define EFD     16
#define NSIG    15
#define EIN     543      // 2*HD + EFD + NSIG
#define XP      552      // edge sX pitch (bf16 elems), 544 used
#define XPN     584      // node sX pitch, 576 used
#define XPP     264      // proj sX pitch, 256 used

typedef __bf16 bf16x8 __attribute__((ext_vector_type(8)));
typedef float  f32x4  __attribute__((ext_vector_type(4)));

__device__ __forceinline__ float lrelu(float x) { return x > 0.f ? x : 0.01f * x; }
__device__ __forceinline__ unsigned short f2bu(float f) {
    __hip_bfloat16 h = __float2bfloat16(f);
    return *reinterpret_cast<unsigned short*>(&h);
}

// ---------------------------------------------------------------------------
// Shared 32xKx256 GEMM core (reg double-buffered). See round-6 notes.
__device__ __forceinline__ void mfma_gemm(
    const unsigned short* sA, int pitch,
    const __hip_bfloat16* Wswz, int KS, int lane, f32x4 acc[2][4])
{
    const int col = lane & 15, quad = lane >> 4;
    const unsigned short* a0p = sA + (size_t)col * pitch + quad * 8;
    const unsigned short* a1p = sA + (size_t)(16 + col) * pitch + quad * 8;
    const __hip_bfloat16* wp = Wswz + lane * 8;
    bf16x8 bc[4], bn[4], a0c, a1c, a0n, a1n;
    #pragma unroll
    for (int nt = 0; nt < 4; ++nt)
        bc[nt] = *reinterpret_cast<const bf16x8*>(wp + (size_t)nt * KS * 512);
    a0c = *reinterpret_cast<const bf16x8*>(a0p);
    a1c = *reinterpret_cast<const bf16x8*>(a1p);
    for (int ks = 0; ks < KS; ++ks) {
        if (ks + 1 < KS) {
            #pragma unroll
            for (int nt = 0; nt < 4; ++nt)
                bn[nt] = *reinterpret_cast<const bf16x8*>(
                    wp + ((size_t)nt * KS + ks + 1) * 512);
            a0n = *reinterpret_cast<const bf16x8*>(a0p + (ks + 1) * 32);
            a1n = *reinterpret_cast<const bf16x8*>(a1p + (ks + 1) * 32);
        }
        #pragma unroll
        for (int nt = 0; nt < 4; ++nt) {
            acc[0][nt] = __builtin_amdgcn_mfma_f32_16x16x32_bf16(a0c, bc[nt], acc[0][nt], 0, 0, 0);
            acc[1][nt] = __builtin_amdgcn_mfma_f32_16x16x32_bf16(a1c, bc[nt], acc[1][nt], 0, 0, 0);
        }
        #pragma unroll
        for (int nt = 0; nt < 4; ++nt) bc[nt] = bn[nt];
        a0c = a0n; a1c = a1n;
    }
}

// ---------------------------------------------------------------------------
__global__ void zero_kernel(float* __restrict__ p, int n) {
    int i = blockIdx.x * 256 + threadIdx.x;
    if (i < n) p[i] = 0.f;
}

// ---------------------------------------------------------------------------
__global__ void wt_swz(const float* __restrict__ src,
                       __hip_bfloat16* __restrict__ dst, int K, int KS) {
    const int g  = blockIdx.x / KS;
    const int ks = blockIdx.x % KS;
    for (int i = threadIdx.x; i < 512; i += 256) {
        const int lane = i >> 3, j = i & 7;
        const int n = g * 16 + (lane & 15);
        const int k = ks * 32 + (lane >> 4) * 8 + j;
        const float v = (k < K) ? src[(size_t)k * 256 + n] : 0.f;
        dst[((size_t)(g * KS + ks) * 64 + lane) * 8 + j] = __float2bfloat16(v);
    }
}

// ---------------------------------------------------------------------------
// Transpose bf16 [N][256] -> [256][N], 64x64 LDS tiles. Grid (N/64, 4).
__global__ __launch_bounds__(256) void vt_kernel(
    const __hip_bfloat16* __restrict__ V, __hip_bfloat16* __restrict__ Vt, int N)
{
    __shared__ unsigned short s[64][72];
    const int r0 = blockIdx.x * 64;       // key rows
    const int c0 = blockIdx.y * 64;       // dim cols
    const int t = threadIdx.x;
    {
        const int r = t & 63, ch = t >> 6;
        #pragma unroll
        for (int i = 0; i < 2; ++i) {
            const int c = (ch + i * 4) * 8;
            *reinterpret_cast<uint4*>(&s[r][c]) =
                *reinterpret_cast<const uint4*>(
                    &V[(size_t)(r0 + r) * HD + c0 + c]);
        }
    }
    __syncthreads();
    {
        const int c = t >> 2, rch = t & 3;
        #pragma unroll
        for (int i = 0; i < 2; ++i) {
            const int rr = (rch + i * 4) * 8;
            unsigned short tmp[8];
            #pragma unroll
            for (int u = 0; u < 8; ++u) tmp[u] = s[rr + u][c];
            *reinterpret_cast<uint4*>(&Vt[(size_t)(c0 + c) * N + r0 + rr]) =
                *reinterpret_cast<uint4*>(tmp);
        }
    }
}

// ---------------------------------------------------------------------------
// Edge MFMA kernel: 32 edges/block (unchanged from round-6).
__global__ __launch_bounds__(256, 4) void edge_mfma(
    const float* __restrict__ coords, const float* __restrict__ h,
    const float* __restrict__ ef,
    const int* __restrict__ src, const int* __restrict__ dst,
    const __hip_bfloat16* __restrict__ W1s, const float* __restrict__ b1,
    const __hip_bfloat16* __restrict__ W2s, const float* __restrict__ b2,
    const __hip_bfloat16* __restrict__ Wc1s, const float* __restrict__ bc1,
    const float* __restrict__ wc2v, const float* __restrict__ bc2,
    float* __restrict__ aggr, float* __restrict__ cnt, float* __restrict__ xsum)
{
    __shared__ unsigned short sX[32][XP];
    __shared__ float sXrel[32][3];
    __shared__ int   sDst[32];
    __shared__ float sRedW[4][32];

    const int tid  = threadIdx.x;
    const int lane = tid & 63;
    const int wave = tid >> 6;
    const int col  = lane & 15;
    const int quad = lane >> 4;
    const int e0   = blockIdx.x * 32;

    for (int i = tid; i < 32 * 128; i += 256) {
        const int row = i >> 7, c4 = i & 127;
        const int node = (c4 < 64) ? src[e0 + row] : dst[e0 + row];
        const float4 v = *reinterpret_cast<const float4*>(
            &h[(size_t)node * HD + (c4 & 63) * 4]);
        ushort4 u = { f2bu(v.x), f2bu(v.y), f2bu(v.z), f2bu(v.w) };
        *reinterpret_cast<ushort4*>(&sX[row][c4 * 4]) = u;
    }
    if (tid < 128) {
        const int row = tid >> 2, c = tid & 3;
        const float4 v = *reinterpret_cast<const float4*>(
            &ef[(size_t)(e0 + row) * EFD + c * 4]);
        ushort4 u = { f2bu(v.x), f2bu(v.y), f2bu(v.z), f2bu(v.w) };
        *reinterpret_cast<ushort4*>(&sX[row][512 + c * 4]) = u;
    }
    if (tid < 32) {
        const int e = e0 + tid;
        const int s = src[e], d = dst[e];
        sDst[tid] = d;
        float d2 = 0.f;
        #pragma unroll
        for (int c = 0; c < 3; ++c) {
            const float xr = coords[s * 3 + c] - coords[d * 3 + c];
            sXrel[tid][c] = xr;
            d2 += xr * xr;
        }
        float sig = 1.0f;
        #pragma unroll
        for (int si = 0; si < NSIG; ++si) {
            sX[tid][528 + si] = f2bu(__expf(-d2 / sig));
            sig *= 1.5f;
        }
        sX[tid][543] = 0;
    }
    __syncthreads();

    f32x4 acc[2][4];

    #pragma unroll
    for (int nt = 0; nt < 4; ++nt) {
        const float bv = b1[wave * 64 + nt * 16 + col];
        acc[0][nt] = { bv, bv, bv, bv };
        acc[1][nt] = { bv, bv, bv, bv };
    }
    mfma_gemm(&sX[0][0], XP, W1s + (size_t)(wave * 4) * 17 * 512, 17, lane, acc);
    __syncthreads();
    #pragma unroll
    for (int mt = 0; mt < 2; ++mt)
        #pragma unroll
        for (int nt = 0; nt < 4; ++nt)
            #pragma unroll
            for (int r = 0; r < 4; ++r)
                sX[mt * 16 + quad * 4 + r][wave * 64 + nt * 16 + col] =
                    f2bu(lrelu(acc[mt][nt][r]));
    __syncthreads();

    #pragma unroll
    for (int nt = 0; nt < 4; ++nt) {
        const float bv = b2[wave * 64 + nt * 16 + col];
        acc[0][nt] = { bv, bv, bv, bv };
        acc[1][nt] = { bv, bv, bv, bv };
    }
    mfma_gemm(&sX[0][0], XP, W2s + (size_t)(wave * 4) * 8 * 512, 8, lane, acc);
    __syncthreads();
    #pragma unroll
    for (int mt = 0; mt < 2; ++mt)
        #pragma unroll
        for (int nt = 0; nt < 4; ++nt)
            #pragma unroll
            for (int r = 0; r < 4; ++r) {
                const int row = mt * 16 + quad * 4 + r;
                const int n   = wave * 64 + nt * 16 + col;
                const float v = acc[mt][nt][r];
                atomicAdd(&aggr[(size_t)sDst[row] * HD + n], v);
                sX[row][n] = f2bu(v);
            }
    __syncthreads();

    #pragma unroll
    for (int nt = 0; nt < 4; ++nt) {
        const float bv = bc1[wave * 64 + nt * 16 + col];
        acc[0][nt] = { bv, bv, bv, bv };
        acc[1][nt] = { bv, bv, bv, bv };
    }
    mfma_gemm(&sX[0][0], XP, Wc1s + (size_t)(wave * 4) * 8 * 512, 8, lane, acc);
    float w2l[4];
    #pragma unroll
    for (int nt = 0; nt < 4; ++nt) w2l[nt] = wc2v[wave * 64 + nt * 16 + col];
    #pragma unroll
    for (int mt = 0; mt < 2; ++mt) {
        float pr[4] = { 0.f, 0.f, 0.f, 0.f };
        #pragma unroll
        for (int nt = 0; nt < 4; ++nt)
            #pragma unroll
            for (int r = 0; r < 4; ++r)
                pr[r] += lrelu(acc[mt][nt][r]) * w2l[nt];
        #pragma unroll
        for (int r = 0; r < 4; ++r) {
            #pragma unroll
            for (int off = 1; off < 16; off <<= 1) pr[r] += __shfl_xor(pr[r], off);
        }
        if (col == 0)
            #pragma unroll
            for (int r = 0; r < 4; ++r)
                sRedW[wave][mt * 16 + quad * 4 + r] = pr[r];
    }
    __syncthreads();
    if (tid < 32) {
        const float p = sRedW[0][tid] + sRedW[1][tid] + sRedW[2][tid] + sRedW[3][tid] + bc2[0];
        const int d = sDst[tid];
        #pragma unroll
        for (int c = 0; c < 3; ++c)
            atomicAdd(&xsum[(size_t)d * 3 + c], sXrel[tid][c] * p);
        atomicAdd(&cnt[d], 1.0f);
    }
}

// ---------------------------------------------------------------------------
// Node MFMA kernel: 32 nodes/block (unchanged from round-6).
__global__ __launch_bounds__(256, 4) void node_mfma(
    const float* __restrict__ aggr, const float* __restrict__ cnt,
    const __hip_bfloat16* __restrict__ cross, const float* __restrict__ orig,
    const float* __restrict__ hfeat,
    const __hip_bfloat16* __restrict__ WN1s, const float* __restrict__ b1,
    const __hip_bfloat16* __restrict__ WN2s, const float* __restrict__ b2,
    float* __restrict__ out)
{
    __shared__ unsigned short sXn[32][XPN];
    __shared__ float sInv[32];

    const int tid  = threadIdx.x;
    const int lane = tid & 63;
    const int wave = tid >> 6;
    const int col  = lane & 15;
    const int quad = lane >> 4;
    const int r0   = blockIdx.x * 32;

    if (tid < 32) sInv[tid] = 1.f / fmaxf(cnt[r0 + tid], 1.f);
    __syncthreads();

    for (int i = tid; i < 32 * 64; i += 256) {
        const int row = i >> 6, c4 = i & 63;
        const float inv = sInv[row];
        const float4 v = *reinterpret_cast<const float4*>(
            &aggr[(size_t)(r0 + row) * HD + c4 * 4]);
        ushort4 u = { f2bu(v.x * inv), f2bu(v.y * inv), f2bu(v.z * inv), f2bu(v.w * inv) };
        *reinterpret_cast<ushort4*>(&sXn[row][c4 * 4]) = u;
    }
    for (int i = tid; i < 32 * 64; i += 256) {
        const int row = i >> 6, c4 = i & 63;
        const ushort4 u = *reinterpret_cast<const ushort4*>(
            &cross[(size_t)(r0 + row) * HD + c4 * 4]);
        *reinterpret_cast<ushort4*>(&sXn[row][256 + c4 * 4]) = u;
    }
    for (int i = tid; i < 32 * 16; i += 256) {
        const int row = i >> 4, c4 = i & 15;
        const float4 v = *reinterpret_cast<const float4*>(
            &orig[(size_t)(r0 + row) * ORIGD + c4 * 4]);
        ushort4 u = { f2bu(v.x), f2bu(v.y), f2bu(v.z), f2bu(v.w) };
        *reinterpret_cast<ushort4*>(&sXn[row][512 + c4 * 4]) = u;
    }
    __syncthreads();

    f32x4 acc[2][4];

    #pragma unroll
    for (int nt = 0; nt < 4; ++nt) {
        const float bv = b1[wave * 64 + nt * 16 + col];
        acc[0][nt] = { bv, bv, bv, bv };
        acc[1][nt] = { bv, bv, bv, bv };
    }
    mfma_gemm(&sXn[0][0], XPN, WN1s + (size_t)(wave * 4) * 18 * 512, 18, lane, acc);
    __syncthreads();
    #pragma unroll
    for (int mt = 0; mt < 2; ++mt)
        #pragma unroll
        for (int nt = 0; nt < 4; ++nt)
            #pragma unroll
            for (int r = 0; r < 4; ++r)
                sXn[mt * 16 + quad * 4 + r][wave * 64 + nt * 16 + col] =
                    f2bu(lrelu(acc[mt][nt][r]));
    __syncthreads();

    #pragma unroll
    for (int nt = 0; nt < 4; ++nt) {
        const float bv = b2[wave * 64 + nt * 16 + col];
        acc[0][nt] = { bv, bv, bv, bv };
        acc[1][nt] = { bv, bv, bv, bv };
    }
    mfma_gemm(&sXn[0][0], XPN, WN2s + (size_t)(wave * 4) * 8 * 512, 8, lane, acc);
    #pragma unroll
    for (int mt = 0; mt < 2; ++mt)
        #pragma unroll
        for (int nt = 0; nt < 4; ++nt)
            #pragma unroll
            for (int r = 0; r < 4; ++r) {
                const int g = r0 + mt * 16 + quad * 4 + r;
                const int n = wave * 64 + nt * 16 + col;
                out[(size_t)g * HD + n] =
                    0.5f * acc[mt][nt][r] + 0.5f * hfeat[(size_t)g * HD + n];
            }
}

// ---------------------------------------------------------------------------
// Projection MFMA (unchanged from round-6).
__global__ __launch_bounds__(256, 4) void proj_mfma(
    const float* __restrict__ X, const __hip_bfloat16* __restrict__ Ws,
    __hip_bfloat16* __restrict__ out, int applyLrelu)
{
    __shared__ unsigned short sXp[32][XPP];
    const int tid  = threadIdx.x;
    const int lane = tid & 63;
    const int wave = tid >> 6;
    const int col  = lane & 15;
    const int quad = lane >> 4;
    const int r0   = blockIdx.x * 32;

    for (int i = tid; i < 32 * 64; i += 256) {
        const int row = i >> 6, c4 = i & 63;
        const float4 v = *reinterpret_cast<const float4*>(
            &X[(size_t)(r0 + row) * HD + c4 * 4]);
        ushort4 u = { f2bu(v.x), f2bu(v.y), f2bu(v.z), f2bu(v.w) };
        *reinterpret_cast<ushort4*>(&sXp[row][c4 * 4]) = u;
    }
    __syncthreads();

    f32x4 acc[2][4];
    #pragma unroll
    for (int nt = 0; nt < 4; ++nt) {
        acc[0][nt] = { 0.f, 0.f, 0.f, 0.f };
        acc[1][nt] = { 0.f, 0.f, 0.f, 0.f };
    }
    mfma_gemm(&sXp[0][0], XPP, Ws + (size_t)(wave * 4) * 8 * 512, 8, lane, acc);
    #pragma unroll
    for (int mt = 0; mt < 2; ++mt)
        #pragma unroll
        for (int nt = 0; nt < 4; ++nt)
            #pragma unroll
            for (int r = 0; r < 4; ++r) {
                float v = acc[mt][nt][r];
                if (applyLrelu) v = lrelu(v);
                out[(size_t)(r0 + mt * 16 + quad * 4 + r) * HD +
                    wave * 64 + nt * 16 + col] = __float2bfloat16(v);
            }
}

// ---------------------------------------------------------------------------
// MFMA flash attention partial. 64 q-rows/block, 32-key tiles.
// V supplied pre-transposed (Vt: bf16 [256][nKeysTotal]) -> pure b128 staging.
__global__ __launch_bounds__(256, 2) void attn_mfma(
    const __hip_bfloat16* __restrict__ Qb, const __hip_bfloat16* __restrict__ Kb,
    const __hip_bfloat16* __restrict__ Vt, const float* __restrict__ maskG,
    float* __restrict__ PO, float* __restrict__ PM, float* __restrict__ PL,
    int M, int nKeysTotal, int chunkKeys, int transposed)
{
    __shared__ unsigned short sK[32][264];
    __shared__ unsigned short sVt[256][40];
    __shared__ unsigned short sP[4][16][40];
    __shared__ float          sMask[64][36];

    const int tid  = threadIdx.x;
    const int lane = tid & 63;
    const int wave = tid >> 6;
    const int col  = lane & 15;
    const int quad = lane >> 4;
    const int R0   = blockIdx.x * 64;
    const int split = blockIdx.y;
    const int jbase = split * chunkKeys;

    bf16x8 qf[8];
    {
        const __hip_bfloat16* qp =
            Qb + (size_t)(R0 + wave * 16 + col) * HD + quad * 8;
        #pragma unroll
        for (int s = 0; s < 8; ++s)
            qf[s] = *reinterpret_cast<const bf16x8*>(qp + 32 * s);
    }

    f32x4 o[16];
    #pragma unroll
    for (int dt = 0; dt < 16; ++dt) { o[dt][0]=0.f; o[dt][1]=0.f; o[dt][2]=0.f; o[dt][3]=0.f; }
    float m[4], l[4];
    #pragma unroll
    for (int r = 0; r < 4; ++r) { m[r] = -INFINITY; l[r] = 0.f; }

    for (int jt = 0; jt < chunkKeys; jt += 32) {
        const int j0 = jbase + jt;
        __syncthreads();
        // ---- stage K [32 keys][256 dims] (b128) ----
        {
            const int key = tid >> 3;
            const int d0  = (tid & 7) * 32;
            const __hip_bfloat16* kp = Kb + (size_t)(j0 + key) * HD + d0;
            #pragma unroll
            for (int i = 0; i < 4; ++i)
                *reinterpret_cast<uint4*>(&sK[key][d0 + 8 * i]) =
                    *reinterpret_cast<const uint4*>(kp + 8 * i);
        }
        // ---- stage V^T [256 dims][32 keys] from global Vt (b128) ----
        {
            const int d  = tid >> 2;
            const int kc = (tid & 3) * 8;
            #pragma unroll
            for (int i = 0; i < 4; ++i) {
                const int dd = d + i * 64;
                *reinterpret_cast<uint4*>(&sVt[dd][kc]) =
                    *reinterpret_cast<const uint4*>(
                        &Vt[(size_t)dd * nKeysTotal + j0 + kc]);
            }
        }
        // ---- stage mask tile [64 rows][32 keys] ----
        if (!transposed) {
            const int row = tid >> 2;
            const int c0  = (tid & 3) * 8;
            #pragma unroll
            for (int i = 0; i < 2; ++i)
                *reinterpret_cast<float4*>(&sMask[row][c0 + 4 * i]) =
                    *reinterpret_cast<const float4*>(
                        &maskG[(size_t)(R0 + row) * N_REC + j0 + c0 + 4 * i]);
        } else {
            const int key = tid >> 3;
            const int r0m = (tid & 7) * 8;
            #pragma unroll
            for (int i = 0; i < 2; ++i) {
                float tmp[4];
                *reinterpret_cast<float4*>(tmp) =
                    *reinterpret_cast<const float4*>(
                        &maskG[(size_t)(j0 + key) * N_REC + R0 + r0m + 4 * i]);
                #pragma unroll
                for (int u = 0; u < 4; ++u)
                    sMask[r0m + 4 * i + u][key] = tmp[u];
            }
        }
        __syncthreads();

        f32x4 sacc[2];
        sacc[0][0]=0.f; sacc[0][1]=0.f; sacc[0][2]=0.f; sacc[0][3]=0.f;
        sacc[1][0]=0.f; sacc[1][1]=0.f; sacc[1][2]=0.f; sacc[1][3]=0.f;
        #pragma unroll
        for (int t = 0; t < 2; ++t) {
            #pragma unroll
            for (int s = 0; s < 8; ++s) {
                bf16x8 kf = *reinterpret_cast<const bf16x8*>(
                    &sK[col + 16 * t][32 * s + quad * 8]);
                sacc[t] = __builtin_amdgcn_mfma_f32_16x16x32_bf16(qf[s], kf, sacc[t], 0, 0, 0);
            }
        }

        float a[2][4];
        #pragma unroll
        for (int t = 0; t < 2; ++t)
            #pragma unroll
            for (int r = 0; r < 4; ++r) {
                const float mv = sMask[wave * 16 + quad * 4 + r][col + 16 * t];
                a[t][r] = mv * sacc[t][r] - 1000.f * (1.f - mv);
            }
        #pragma unroll
        for (int r = 0; r < 4; ++r) {
            float mx = fmaxf(a[0][r], a[1][r]);
            #pragma unroll
            for (int off = 1; off < 16; off <<= 1)
                mx = fmaxf(mx, __shfl_xor(mx, off));
            const float mn = fmaxf(m[r], mx);
            const float c  = __expf(m[r] - mn);
            m[r] = mn;
            const float p0 = __expf(a[0][r] - mn);
            const float p1 = __expf(a[1][r] - mn);
            sP[wave][quad * 4 + r][col]      = f2bu(p0);
            sP[wave][quad * 4 + r][col + 16] = f2bu(p1);
            float ps = p0 + p1;
            #pragma unroll
            for (int off = 1; off < 16; off <<= 1)
                ps += __shfl_xor(ps, off);
            l[r] = l[r] * c + ps;
            #pragma unroll
            for (int dt = 0; dt < 16; ++dt) o[dt][r] *= c;
        }

        bf16x8 pf = *reinterpret_cast<const bf16x8*>(&sP[wave][col][quad * 8]);
        #pragma unroll
        for (int dt = 0; dt < 16; ++dt) {
            bf16x8 vf = *reinterpret_cast<const bf16x8*>(
                &sVt[col + 16 * dt][quad * 8]);
            o[dt] = __builtin_amdgcn_mfma_f32_16x16x32_bf16(pf, vf, o[dt], 0, 0, 0);
        }
    }

    #pragma unroll
    for (int dt = 0; dt < 16; ++dt)
        #pragma unroll
        for (int r = 0; r < 4; ++r) {
            const int row = R0 + wave * 16 + quad * 4 + r;
            PO[((size_t)split * M + row) * HD + dt * 16 + col] = o[dt][r];
        }
    if (col == 0) {
        #pragma unroll
        for (int r = 0; r < 4; ++r) {
            const int row = R0 + wave * 16 + quad * 4 + r;
            PM[(size_t)split * M + row] = m[r];
            PL[(size_t)split * M + row] = l[r];
        }
    }
}

// ---------------------------------------------------------------------------
__global__ void attn_combine(
    const float* __restrict__ PO, const float* __restrict__ PM,
    const float* __restrict__ PL, __hip_bfloat16* __restrict__ Out,
    int M, int nchunks)
{
    const int idx = blockIdx.x * 256 + threadIdx.x;
    const int row = idx >> 8;
    float mmax = -INFINITY;
    for (int c = 0; c < nchunks; ++c) mmax = fmaxf(mmax, PM[(size_t)c * M + row]);
    float denom = 0.f, acc = 0.f;
    for (int c = 0; c < nchunks; ++c) {
        const float w = __expf(PM[(size_t)c * M + row] - mmax);
        denom += PL[(size_t)c * M + row] * w;
        acc   += PO[(size_t)c * M * HD + idx] * w;
    }
    Out[idx] = __float2bfloat16(acc / denom);
}

// ---------------------------------------------------------------------------
__global__ void coords_fin(
    const float* __restrict__ coords, const float* __restrict__ origc,
    const float* __restrict__ xsum, const float* __restrict__ cnt,
    float* __restrict__ out, int n)
{
    const int i = blockIdx.x * 256 + threadIdx.x;
    if (i >= n * 3) return;
    const int node = i / 3;
    const float inv = 1.f / fmaxf(cnt[node], 1.f);
    out[i] = 0.25f * origc[i] + 0.75f * coords[i] + xsum[i] * inv;
}

// ---------------------------------------------------------------------------
extern "C" void kernel_launch(void* const* d_in, const int* in_sizes, int n_in,
                              void* d_out, int out_size, void* d_ws, size_t ws_size,
                              hipStream_t stream)
{
    const float* coords_lig = (const float*)d_in[0];
    const float* h_lig      = (const float*)d_in[1];
    const float* orig_lig   = (const float*)d_in[2];
    const float* origc_lig  = (const float*)d_in[3];
    const float* coords_rec = (const float*)d_in[4];
    const float* h_rec      = (const float*)d_in[5];
    const float* orig_rec   = (const float*)d_in[6];
    const float* origc_rec  = (const float*)d_in[7];
    const float* mask       = (const float*)d_in[8];
    const float* lig_ef     = (const float*)d_in[9];
    const float* rec_ef     = (const float*)d_in[10];
    const int* lig_src = (const int*)d_in[11];
    const int* lig_dst = (const int*)d_in[12];
    const int* rec_src = (const int*)d_in[13];
    const int* rec_dst = (const int*)d_in[14];
    const float* le_w1 = (const float*)d_in[15];
    const float* le_b1 = (const float*)d_in[16];
    const float* le_w2 = (const float*)d_in[17];
    const float* le_b2 = (const float*)d_in[18];
    const float* re_w1 = (const float*)d_in[19];
    const float* re_b1 = (const float*)d_in[20];
    const float* re_w2 = (const float*)d_in[21];
    const float* re_b2 = (const float*)d_in[22];
    const float* aql_w = (const float*)d_in[23];
    const float* akl_w = (const float*)d_in[24];
    const float* avl_w = (const float*)d_in[25];
    const float* aqr_w = (const float*)d_in[26];
    const float* akr_w = (const float*)d_in[27];
    const float* avr_w = (const float*)d_in[28];
    const float* nl_w1 = (const float*)d_in[29];
    const float* nl_b1 = (const float*)d_in[30];
    const float* nl_w2 = (const float*)d_in[31];
    const float* nl_b2 = (const float*)d_in[32];
    const float* nr_w1 = (const float*)d_in[33];
    const float* nr_b1 = (const float*)d_in[34];
    const float* nr_w2 = (const float*)d_in[35];
    const float* nr_b2 = (const float*)d_in[36];
    const float* cl_w1 = (const float*)d_in[37];
    const float* cl_b1 = (const float*)d_in[38];
    const float* cl_w2 = (const float*)d_in[39];
    const float* cl_b2 = (const float*)d_in[40];
    const float* cr_w1 = (const float*)d_in[41];
    const float* cr_b1 = (const float*)d_in[42];
    const float* cr_w2 = (const float*)d_in[43];
    const float* cr_b2 = (const float*)d_in[44];

    float* out = (float*)d_out;
    float* wsf = (float*)d_ws;

    // ---- fp32 accumulator zone (zeroed) ----
    const size_t AGGRL = 0;
    const size_t AGGRR = AGGRL + (size_t)N_LIG * HD;
    const size_t CNTL  = AGGRR + (size_t)N_REC * HD;
    const size_t CNTR  = CNTL + N_LIG;
    const size_t XSUML = CNTR + N_REC;
    const size_t XSUMR = XSUML + (size_t)N_LIG * 3;
    const size_t ZEND  = XSUMR + (size_t)N_REC * 3;

    // ---- bf16 zone (fixed offsets, right after ZEND) ----
    __hip_bfloat16* wsb = (__hip_bfloat16*)(wsf + ZEND);
    const size_t QL  = 0;
    const size_t KL  = QL + (size_t)N_LIG * HD;
    const size_t VL  = KL + (size_t)N_LIG * HD;
    const size_t QR  = VL + (size_t)N_LIG * HD;
    const size_t KR  = QR + (size_t)N_REC * HD;
    const size_t VR  = KR + (size_t)N_REC * HD;
    const size_t CRL = VR + (size_t)N_REC * HD;
    const size_t CRR = CRL + (size_t)N_LIG * HD;
    const size_t VTL = CRR + (size_t)N_REC * HD;          // V^T lig [256][N_LIG]
    const size_t VTR = VTL + (size_t)N_LIG * HD;          // V^T rec [256][N_REC]
    const size_t EW1SZ = (size_t)16 * 17 * 512;
    const size_t KW256 = (size_t)16 * 8 * 512;
    const size_t NW1SZ = (size_t)16 * 18 * 512;
    const size_t SW_EL1 = VTR + (size_t)N_REC * HD;
    const size_t SW_EL2 = SW_EL1 + EW1SZ;
    const size_t SW_EC1 = SW_EL2 + KW256;
    const size_t SW_NL1 = SW_EC1 + KW256;
    const size_t SW_NL2 = SW_NL1 + NW1SZ;
    const size_t SW_ER1 = SW_NL2 + KW256;
    const size_t SW_ER2 = SW_ER1 + EW1SZ;
    const size_t SW_EC1R = SW_ER2 + KW256;
    const size_t SW_NR1 = SW_EC1R + KW256;
    const size_t SW_NR2 = SW_NR1 + NW1SZ;
    const size_t SW_PQL = SW_NR2 + KW256;
    const size_t SW_PKL = SW_PQL + KW256;
    const size_t SW_PVL = SW_PKL + KW256;
    const size_t SW_PQR = SW_PVL + KW256;
    const size_t SW_PKR = SW_PQR + KW256;
    const size_t SW_PVR = SW_PKR + KW256;
    const size_t BF_END = SW_PVR + KW256;                 // bf16 elems

    // ---- split-K partial zone (fp32, after bf16 zone), dynamic splits ----
    float* wsp = (float*)(wsb + ((BF_END + 1) & ~(size_t)1));
    const size_t baseBytes = (size_t)((char*)wsp - (char*)d_ws);
    // choose splits: prefer 16 (lig) / 4 (rec) if workspace allows
    int SL = 16, SR = 4;
    {
        const size_t poElems16 = (size_t)16 * N_LIG * HD;   // == 4*N_REC*HD
        const size_t need16 = baseBytes +
            (poElems16 + 2 * (size_t)16 * N_LIG) * sizeof(float);
        if (ws_size < need16) { SL = 8; SR = 2; }
    }
    const size_t PO_ = 0;
    const size_t PM_ = PO_ + (size_t)SL * N_LIG * HD;
    const size_t PL_ = PM_ + (size_t)SL * N_LIG;

    const size_t O_XL = 0;
    const size_t O_HL = O_XL + (size_t)N_LIG * 3;
    const size_t O_XR = O_HL + (size_t)N_LIG * HD;
    const size_t O_HR = O_XR + (size_t)N_REC * 3;

    // 1) zero atomic accumulators
    zero_kernel<<<((int)ZEND + 255) / 256, 256, 0, stream>>>(wsf, (int)ZEND);

    // 2) weight swizzles
    wt_swz<<<16 * 17, 256, 0, stream>>>(le_w1, wsb + SW_EL1, EIN, 17);
    wt_swz<<<16 * 8,  256, 0, stream>>>(le_w2, wsb + SW_EL2, 256, 8);
    wt_swz<<<16 * 8,  256, 0, stream>>>(cl_w1, wsb + SW_EC1, 256, 8);
    wt_swz<<<16 * 18, 256, 0, stream>>>(nl_w1, wsb + SW_NL1, 576, 18);
    wt_swz<<<16 * 8,  256, 0, stream>>>(nl_w2, wsb + SW_NL2, 256, 8);
    wt_swz<<<16 * 17, 256, 0, stream>>>(re_w1, wsb + SW_ER1, EIN, 17);
    wt_swz<<<16 * 8,  256, 0, stream>>>(re_w2, wsb + SW_ER2, 256, 8);
    wt_swz<<<16 * 8,  256, 0, stream>>>(cr_w1, wsb + SW_EC1R, 256, 8);
    wt_swz<<<16 * 18, 256, 0, stream>>>(nr_w1, wsb + SW_NR1, 576, 18);
    wt_swz<<<16 * 8,  256, 0, stream>>>(nr_w2, wsb + SW_NR2, 256, 8);
    wt_swz<<<16 * 8,  256, 0, stream>>>(aql_w, wsb + SW_PQL, 256, 8);
    wt_swz<<<16 * 8,  256, 0, stream>>>(akl_w, wsb + SW_PKL, 256, 8);
    wt_swz<<<16 * 8,  256, 0, stream>>>(avl_w, wsb + SW_PVL, 256, 8);
    wt_swz<<<16 * 8,  256, 0, stream>>>(aqr_w, wsb + SW_PQR, 256, 8);
    wt_swz<<<16 * 8,  256, 0, stream>>>(akr_w, wsb + SW_PKR, 256, 8);
    wt_swz<<<16 * 8,  256, 0, stream>>>(avr_w, wsb + SW_PVR, 256, 8);

    // 3) edge MFMA kernels
    edge_mfma<<<E_LIG_N / 32, 256, 0, stream>>>(
        coords_lig, h_lig, lig_ef, lig_src, lig_dst,
        wsb + SW_EL1, le_b1, wsb + SW_EL2, le_b2, wsb + SW_EC1, cl_b1, cl_w2, cl_b2,
        wsf + AGGRL, wsf + CNTL, wsf + XSUML);
    edge_mfma<<<E_REC_N / 32, 256, 0, stream>>>(
        coords_rec, h_rec, rec_ef, rec_src, rec_dst,
        wsb + SW_ER1, re_b1, wsb + SW_ER2, re_b2, wsb + SW_EC1R, cr_b1, cr_w2, cr_b2,
        wsf + AGGRR, wsf + CNTR, wsf + XSUMR);

    // 4) projections -> bf16 (MFMA), then V^T
    proj_mfma<<<N_LIG / 32, 256, 0, stream>>>(h_lig, wsb + SW_PQL, wsb + QL, 1);
    proj_mfma<<<N_LIG / 32, 256, 0, stream>>>(h_lig, wsb + SW_PKL, wsb + KL, 1);
    proj_mfma<<<N_LIG / 32, 256, 0, stream>>>(h_lig, wsb + SW_PVL, wsb + VL, 0);
    proj_mfma<<<N_REC / 32, 256, 0, stream>>>(h_rec, wsb + SW_PQR, wsb + QR, 1);
    proj_mfma<<<N_REC / 32, 256, 0, stream>>>(h_rec, wsb + SW_PKR, wsb + KR, 1);
    proj_mfma<<<N_REC / 32, 256, 0, stream>>>(h_rec, wsb + SW_PVR, wsb + VR, 0);
    {
        dim3 gtl(N_LIG / 64, 4);
        vt_kernel<<<gtl, 256, 0, stream>>>(wsb + VL, wsb + VTL, N_LIG);
        dim3 gtr(N_REC / 64, 4);
        vt_kernel<<<gtr, 256, 0, stream>>>(wsb + VR, wsb + VTR, N_REC);
    }

    // 5) MFMA flash attention, split-K + combine
    {
        dim3 gl(N_LIG / 64, SL);
        attn_mfma<<<gl, 256, 0, stream>>>(wsb + QL, wsb + KR, wsb + VTR, mask,
                                          wsp + PO_, wsp + PM_, wsp + PL_,
                                          N_LIG, N_REC, N_REC / SL, 0);
        attn_combine<<<N_LIG, 256, 0, stream>>>(
            wsp + PO_, wsp + PM_, wsp + PL_, wsb + CRL, N_LIG, SL);

        dim3 gr(N_REC / 64, SR);
        attn_mfma<<<gr, 256, 0, stream>>>(wsb + QR, wsb + KL, wsb + VTL, mask,
                                          wsp + PO_, wsp + PM_, wsp + PL_,
                                          N_REC, N_LIG, N_LIG / SR, 1);
        attn_combine<<<N_REC, 256, 0, stream>>>(
            wsp + PO_, wsp + PM_, wsp + PL_, wsb + CRR, N_REC, SR);
    }

    // 6) coordinate outputs
    coords_fin<<<(N_LIG * 3 + 255) / 256, 256, 0, stream>>>(
        coords_lig, origc_lig, wsf + XSUML, wsf + CNTL, out + O_XL, N_LIG);
    coords_fin<<<(N_REC * 3 + 255) / 256, 256, 0, stream>>>(
        coords_rec, origc_rec, wsf + XSUMR, wsf + CNTR, out + O_XR, N_REC);

    // 7) node MFMA kernels
    node_mfma<<<N_LIG / 32, 256, 0, stream>>>(
        wsf + AGGRL, wsf + CNTL, wsb + CRL, orig_lig, h_lig,
        wsb + SW_NL1, nl_b1, wsb + SW_NL2, nl_b2, out + O_HL);
    node_mfma<<<N_REC / 32, 256, 0, stream>>>(
        wsf + AGGRR, wsf + CNTR, wsb + CRR, orig_rec, h_rec,
        wsb + SW_NR1, nr_b1, wsb + SW_NR2, nr_b2, out + O_HR);

    (void)in_sizes; (void)n_in; (void)out_size;
}

// Round 8
// 1576.206 us; speedup vs baseline: 12.8349x; 1.0046x over previous
//
#include <hip/hip_runtime.h>
#include <hip/hip_bf16.h>

// ---------------------------------------------------------------------------
// IEGMN layer, MI355X round-8: fragment-swizzled K/V attention, 32-row blocks.
//   zero_kernel  : zero atomic accumulators
//   wt_swz       : pack weights fp32[K][256] -> bf16 fragment-ordered blobs
//   edge_mfma    : gather + RBF + edge MLP + coords MLP + atomic seg-sums
//   proj_mfma    : q/k/v projections -> bf16 ws (MFMA)
//   kswz_kernel  : K [N][256] -> fragment-ordered blob (16B-chunk permutation)
//   vswz_kernel  : V [N][256] -> fragment-ordered blob (LDS-tiled transpose)
//   attn_mfma    : flash attention partial (split-K), MFMA 16x16x32 bf16
//   attn_combine : merge splits -> bf16 cross features
//   coords_fin   : x_ev -> out (fp32)
//   node_mfma    : node MLP + skip -> out (fp32, MFMA)
// ---------------------------------------------------------------------------

#define N_LIG   4096
#define N_REC   16384
#define E_LIG_N 65536
#define E_REC_N 262144
#define HD      256
#define ORIGD   64
#define EFD     16
#define NSIG    15
#define EIN     543      // 2*HD + EFD + NSIG
#define XP      552      // edge sX pitch (bf16 elems), 544 used
#define XPN     584      // node sX pitch, 576 used
#define XPP     264      // proj sX pitch, 256 used

typedef __bf16 bf16x8 __attribute__((ext_vector_type(8)));
typedef float  f32x4  __attribute__((ext_vector_type(4)));

__device__ __forceinline__ float lrelu(float x) { return x > 0.f ? x : 0.01f * x; }
__device__ __forceinline__ unsigned short f2bu(float f) {
    __hip_bfloat16 h = __float2bfloat16(f);
    return *reinterpret_cast<unsigned short*>(&h);
}

// ---------------------------------------------------------------------------
// Shared 32xKx256 GEMM core (reg double-buffered).
__device__ __forceinline__ void mfma_gemm(
    const unsigned short* sA, int pitch,
    const __hip_bfloat16* Wswz, int KS, int lane, f32x4 acc[2][4])
{
    const int col = lane & 15, quad = lane >> 4;
    const unsigned short* a0p = sA + (size_t)col * pitch + quad * 8;
    const unsigned short* a1p = sA + (size_t)(16 + col) * pitch + quad * 8;
    const __hip_bfloat16* wp = Wswz + lane * 8;
    bf16x8 bc[4], bn[4], a0c, a1c, a0n, a1n;
    #pragma unroll
    for (int nt = 0; nt < 4; ++nt)
        bc[nt] = *reinterpret_cast<const bf16x8*>(wp + (size_t)nt * KS * 512);
    a0c = *reinterpret_cast<const bf16x8*>(a0p);
    a1c = *reinterpret_cast<const bf16x8*>(a1p);
    for (int ks = 0; ks < KS; ++ks) {
        if (ks + 1 < KS) {
            #pragma unroll
            for (int nt = 0; nt < 4; ++nt)
                bn[nt] = *reinterpret_cast<const bf16x8*>(
                    wp + ((size_t)nt * KS + ks + 1) * 512);
            a0n = *reinterpret_cast<const bf16x8*>(a0p + (ks + 1) * 32);
            a1n = *reinterpret_cast<const bf16x8*>(a1p + (ks + 1) * 32);
        }
        #pragma unroll
        for (int nt = 0; nt < 4; ++nt) {
            acc[0][nt] = __builtin_amdgcn_mfma_f32_16x16x32_bf16(a0c, bc[nt], acc[0][nt], 0, 0, 0);
            acc[1][nt] = __builtin_amdgcn_mfma_f32_16x16x32_bf16(a1c, bc[nt], acc[1][nt], 0, 0, 0);
        }
        #pragma unroll
        for (int nt = 0; nt < 4; ++nt) bc[nt] = bn[nt];
        a0c = a0n; a1c = a1n;
    }
}

// ---------------------------------------------------------------------------
__global__ void zero_kernel(float* __restrict__ p, int n) {
    int i = blockIdx.x * 256 + threadIdx.x;
    if (i < n) p[i] = 0.f;
}

// ---------------------------------------------------------------------------
__global__ void wt_swz(const float* __restrict__ src,
                       __hip_bfloat16* __restrict__ dst, int K, int KS) {
    const int g  = blockIdx.x / KS;
    const int ks = blockIdx.x % KS;
    for (int i = threadIdx.x; i < 512; i += 256) {
        const int lane = i >> 3, j = i & 7;
        const int n = g * 16 + (lane & 15);
        const int k = ks * 32 + (lane >> 4) * 8 + j;
        const float v = (k < K) ? src[(size_t)k * 256 + n] : 0.f;
        dst[((size_t)(g * KS + ks) * 64 + lane) * 8 + j] = __float2bfloat16(v);
    }
}

// ---------------------------------------------------------------------------
// K fragment swizzle: blob[((key/16)*8+s)*512 + lane*8 + j]
//   = K[(key/16)*16 + (lane&15)][s*32 + (lane>>4)*8 + j].  Pure 16B permute.
__global__ __launch_bounds__(256) void kswz_kernel(
    const __hip_bfloat16* __restrict__ K, __hip_bfloat16* __restrict__ blob)
{
    const int c = blockIdx.x * 256 + threadIdx.x;   // chunk id, N*32 total
    const int lane = c & 63;
    const int s    = (c >> 6) & 7;
    const int kt   = c >> 9;
    const __hip_bfloat16* src =
        K + (size_t)(kt * 16 + (lane & 15)) * HD + s * 32 + (lane >> 4) * 8;
    *reinterpret_cast<uint4*>(blob + (size_t)c * 8) =
        *reinterpret_cast<const uint4*>(src);
}

// ---------------------------------------------------------------------------
// V fragment swizzle: blob[((key32)*16+dt)*512 + lane*8 + j]
//   = V[key32*32 + (lane>>4)*8 + j][dt*16 + (lane&15)].  One 32-key tile/block.
__global__ __launch_bounds__(256) void vswz_kernel(
    const __hip_bfloat16* __restrict__ V, __hip_bfloat16* __restrict__ blob)
{
    __shared__ unsigned short s[32][264];
    const int jt  = blockIdx.x;
    const int tid = threadIdx.x;
    {   // stage V rows [32][256] (b128)
        const int row = tid >> 3;
        const int d0  = (tid & 7) * 32;
        const __hip_bfloat16* vp = V + (size_t)(jt * 32 + row) * HD + d0;
        #pragma unroll
        for (int i = 0; i < 4; ++i)
            *reinterpret_cast<uint4*>(&s[row][d0 + 8 * i]) =
                *reinterpret_cast<const uint4*>(vp + 8 * i);
    }
    __syncthreads();
    {
        const int w    = tid >> 6;
        const int lane = tid & 63;
        const int col  = lane & 15;
        const int quad = lane >> 4;
        #pragma unroll
        for (int i = 0; i < 4; ++i) {
            const int dt = w + i * 4;
            unsigned short tmp[8];
            #pragma unroll
            for (int j = 0; j < 8; ++j)
                tmp[j] = s[quad * 8 + j][dt * 16 + col];
            *reinterpret_cast<uint4*>(
                blob + ((size_t)(jt * 16 + dt) * 64 + lane) * 8) =
                *reinterpret_cast<uint4*>(tmp);
        }
    }
}

// ---------------------------------------------------------------------------
// Edge MFMA kernel: 32 edges/block (unchanged).
__global__ __launch_bounds__(256, 4) void edge_mfma(
    const float* __restrict__ coords, const float* __restrict__ h,
    const float* __restrict__ ef,
    const int* __restrict__ src, const int* __restrict__ dst,
    const __hip_bfloat16* __restrict__ W1s, const float* __restrict__ b1,
    const __hip_bfloat16* __restrict__ W2s, const float* __restrict__ b2,
    const __hip_bfloat16* __restrict__ Wc1s, const float* __restrict__ bc1,
    const float* __restrict__ wc2v, const float* __restrict__ bc2,
    float* __restrict__ aggr, float* __restrict__ cnt, float* __restrict__ xsum)
{
    __shared__ unsigned short sX[32][XP];
    __shared__ float sXrel[32][3];
    __shared__ int   sDst[32];
    __shared__ float sRedW[4][32];

    const int tid  = threadIdx.x;
    const int lane = tid & 63;
    const int wave = tid >> 6;
    const int col  = lane & 15;
    const int quad = lane >> 4;
    const int e0   = blockIdx.x * 32;

    for (int i = tid; i < 32 * 128; i += 256) {
        const int row = i >> 7, c4 = i & 127;
        const int node = (c4 < 64) ? src[e0 + row] : dst[e0 + row];
        const float4 v = *reinterpret_cast<const float4*>(
            &h[(size_t)node * HD + (c4 & 63) * 4]);
        ushort4 u = { f2bu(v.x), f2bu(v.y), f2bu(v.z), f2bu(v.w) };
        *reinterpret_cast<ushort4*>(&sX[row][c4 * 4]) = u;
    }
    if (tid < 128) {
        const int row = tid >> 2, c = tid & 3;
        const float4 v = *reinterpret_cast<const float4*>(
            &ef[(size_t)(e0 + row) * EFD + c * 4]);
        ushort4 u = { f2bu(v.x), f2bu(v.y), f2bu(v.z), f2bu(v.w) };
        *reinterpret_cast<ushort4*>(&sX[row][512 + c * 4]) = u;
    }
    if (tid < 32) {
        const int e = e0 + tid;
        const int s = src[e], d = dst[e];
        sDst[tid] = d;
        float d2 = 0.f;
        #pragma unroll
        for (int c = 0; c < 3; ++c) {
            const float xr = coords[s * 3 + c] - coords[d * 3 + c];
            sXrel[tid][c] = xr;
            d2 += xr * xr;
        }
        float sig = 1.0f;
        #pragma unroll
        for (int si = 0; si < NSIG; ++si) {
            sX[tid][528 + si] = f2bu(__expf(-d2 / sig));
            sig *= 1.5f;
        }
        sX[tid][543] = 0;
    }
    __syncthreads();

    f32x4 acc[2][4];

    #pragma unroll
    for (int nt = 0; nt < 4; ++nt) {
        const float bv = b1[wave * 64 + nt * 16 + col];
        acc[0][nt] = { bv, bv, bv, bv };
        acc[1][nt] = { bv, bv, bv, bv };
    }
    mfma_gemm(&sX[0][0], XP, W1s + (size_t)(wave * 4) * 17 * 512, 17, lane, acc);
    __syncthreads();
    #pragma unroll
    for (int mt = 0; mt < 2; ++mt)
        #pragma unroll
        for (int nt = 0; nt < 4; ++nt)
            #pragma unroll
            for (int r = 0; r < 4; ++r)
                sX[mt * 16 + quad * 4 + r][wave * 64 + nt * 16 + col] =
                    f2bu(lrelu(acc[mt][nt][r]));
    __syncthreads();

    #pragma unroll
    for (int nt = 0; nt < 4; ++nt) {
        const float bv = b2[wave * 64 + nt * 16 + col];
        acc[0][nt] = { bv, bv, bv, bv };
        acc[1][nt] = { bv, bv, bv, bv };
    }
    mfma_gemm(&sX[0][0], XP, W2s + (size_t)(wave * 4) * 8 * 512, 8, lane, acc);
    __syncthreads();
    #pragma unroll
    for (int mt = 0; mt < 2; ++mt)
        #pragma unroll
        for (int nt = 0; nt < 4; ++nt)
            #pragma unroll
            for (int r = 0; r < 4; ++r) {
                const int row = mt * 16 + quad * 4 + r;
                const int n   = wave * 64 + nt * 16 + col;
                const float v = acc[mt][nt][r];
                atomicAdd(&aggr[(size_t)sDst[row] * HD + n], v);
                sX[row][n] = f2bu(v);
            }
    __syncthreads();

    #pragma unroll
    for (int nt = 0; nt < 4; ++nt) {
        const float bv = bc1[wave * 64 + nt * 16 + col];
        acc[0][nt] = { bv, bv, bv, bv };
        acc[1][nt] = { bv, bv, bv, bv };
    }
    mfma_gemm(&sX[0][0], XP, Wc1s + (size_t)(wave * 4) * 8 * 512, 8, lane, acc);
    float w2l[4];
    #pragma unroll
    for (int nt = 0; nt < 4; ++nt) w2l[nt] = wc2v[wave * 64 + nt * 16 + col];
    #pragma unroll
    for (int mt = 0; mt < 2; ++mt) {
        float pr[4] = { 0.f, 0.f, 0.f, 0.f };
        #pragma unroll
        for (int nt = 0; nt < 4; ++nt)
            #pragma unroll
            for (int r = 0; r < 4; ++r)
                pr[r] += lrelu(acc[mt][nt][r]) * w2l[nt];
        #pragma unroll
        for (int r = 0; r < 4; ++r) {
            #pragma unroll
            for (int off = 1; off < 16; off <<= 1) pr[r] += __shfl_xor(pr[r], off);
        }
        if (col == 0)
            #pragma unroll
            for (int r = 0; r < 4; ++r)
                sRedW[wave][mt * 16 + quad * 4 + r] = pr[r];
    }
    __syncthreads();
    if (tid < 32) {
        const float p = sRedW[0][tid] + sRedW[1][tid] + sRedW[2][tid] + sRedW[3][tid] + bc2[0];
        const int d = sDst[tid];
        #pragma unroll
        for (int c = 0; c < 3; ++c)
            atomicAdd(&xsum[(size_t)d * 3 + c], sXrel[tid][c] * p);
        atomicAdd(&cnt[d], 1.0f);
    }
}

// ---------------------------------------------------------------------------
// Node MFMA kernel: 32 nodes/block (unchanged).
__global__ __launch_bounds__(256, 4) void node_mfma(
    const float* __restrict__ aggr, const float* __restrict__ cnt,
    const __hip_bfloat16* __restrict__ cross, const float* __restrict__ orig,
    const float* __restrict__ hfeat,
    const __hip_bfloat16* __restrict__ WN1s, const float* __restrict__ b1,
    const __hip_bfloat16* __restrict__ WN2s, const float* __restrict__ b2,
    float* __restrict__ out)
{
    __shared__ unsigned short sXn[32][XPN];
    __shared__ float sInv[32];

    const int tid  = threadIdx.x;
    const int lane = tid & 63;
    const int wave = tid >> 6;
    const int col  = lane & 15;
    const int quad = lane >> 4;
    const int r0   = blockIdx.x * 32;

    if (tid < 32) sInv[tid] = 1.f / fmaxf(cnt[r0 + tid], 1.f);
    __syncthreads();

    for (int i = tid; i < 32 * 64; i += 256) {
        const int row = i >> 6, c4 = i & 63;
        const float inv = sInv[row];
        const float4 v = *reinterpret_cast<const float4*>(
            &aggr[(size_t)(r0 + row) * HD + c4 * 4]);
        ushort4 u = { f2bu(v.x * inv), f2bu(v.y * inv), f2bu(v.z * inv), f2bu(v.w * inv) };
        *reinterpret_cast<ushort4*>(&sXn[row][c4 * 4]) = u;
    }
    for (int i = tid; i < 32 * 64; i += 256) {
        const int row = i >> 6, c4 = i & 63;
        const ushort4 u = *reinterpret_cast<const ushort4*>(
            &cross[(size_t)(r0 + row) * HD + c4 * 4]);
        *reinterpret_cast<ushort4*>(&sXn[row][256 + c4 * 4]) = u;
    }
    for (int i = tid; i < 32 * 16; i += 256) {
        const int row = i >> 4, c4 = i & 15;
        const float4 v = *reinterpret_cast<const float4*>(
            &orig[(size_t)(r0 + row) * ORIGD + c4 * 4]);
        ushort4 u = { f2bu(v.x), f2bu(v.y), f2bu(v.z), f2bu(v.w) };
        *reinterpret_cast<ushort4*>(&sXn[row][512 + c4 * 4]) = u;
    }
    __syncthreads();

    f32x4 acc[2][4];

    #pragma unroll
    for (int nt = 0; nt < 4; ++nt) {
        const float bv = b1[wave * 64 + nt * 16 + col];
        acc[0][nt] = { bv, bv, bv, bv };
        acc[1][nt] = { bv, bv, bv, bv };
    }
    mfma_gemm(&sXn[0][0], XPN, WN1s + (size_t)(wave * 4) * 18 * 512, 18, lane, acc);
    __syncthreads();
    #pragma unroll
    for (int mt = 0; mt < 2; ++mt)
        #pragma unroll
        for (int nt = 0; nt < 4; ++nt)
            #pragma unroll
            for (int r = 0; r < 4; ++r)
                sXn[mt * 16 + quad * 4 + r][wave * 64 + nt * 16 + col] =
                    f2bu(lrelu(acc[mt][nt][r]));
    __syncthreads();

    #pragma unroll
    for (int nt = 0; nt < 4; ++nt) {
        const float bv = b2[wave * 64 + nt * 16 + col];
        acc[0][nt] = { bv, bv, bv, bv };
        acc[1][nt] = { bv, bv, bv, bv };
    }
    mfma_gemm(&sXn[0][0], XPN, WN2s + (size_t)(wave * 4) * 8 * 512, 8, lane, acc);
    #pragma unroll
    for (int mt = 0; mt < 2; ++mt)
        #pragma unroll
        for (int nt = 0; nt < 4; ++nt)
            #pragma unroll
            for (int r = 0; r < 4; ++r) {
                const int g = r0 + mt * 16 + quad * 4 + r;
                const int n = wave * 64 + nt * 16 + col;
                out[(size_t)g * HD + n] =
                    0.5f * acc[mt][nt][r] + 0.5f * hfeat[(size_t)g * HD + n];
            }
}

// ---------------------------------------------------------------------------
// Projection MFMA (unchanged).
__global__ __launch_bounds__(256, 4) void proj_mfma(
    const float* __restrict__ X, const __hip_bfloat16* __restrict__ Ws,
    __hip_bfloat16* __restrict__ out, int applyLrelu)
{
    __shared__ unsigned short sXp[32][XPP];
    const int tid  = threadIdx.x;
    const int lane = tid & 63;
    const int wave = tid >> 6;
    const int col  = lane & 15;
    const int quad = lane >> 4;
    const int r0   = blockIdx.x * 32;

    for (int i = tid; i < 32 * 64; i += 256) {
        const int row = i >> 6, c4 = i & 63;
        const float4 v = *reinterpret_cast<const float4*>(
            &X[(size_t)(r0 + row) * HD + c4 * 4]);
        ushort4 u = { f2bu(v.x), f2bu(v.y), f2bu(v.z), f2bu(v.w) };
        *reinterpret_cast<ushort4*>(&sXp[row][c4 * 4]) = u;
    }
    __syncthreads();

    f32x4 acc[2][4];
    #pragma unroll
    for (int nt = 0; nt < 4; ++nt) {
        acc[0][nt] = { 0.f, 0.f, 0.f, 0.f };
        acc[1][nt] = { 0.f, 0.f, 0.f, 0.f };
    }
    mfma_gemm(&sXp[0][0], XPP, Ws + (size_t)(wave * 4) * 8 * 512, 8, lane, acc);
    #pragma unroll
    for (int mt = 0; mt < 2; ++mt)
        #pragma unroll
        for (int nt = 0; nt < 4; ++nt)
            #pragma unroll
            for (int r = 0; r < 4; ++r) {
                float v = acc[mt][nt][r];
                if (applyLrelu) v = lrelu(v);
                out[(size_t)(r0 + mt * 16 + quad * 4 + r) * HD +
                    wave * 64 + nt * 16 + col] = __float2bfloat16(v);
            }
}

// ---------------------------------------------------------------------------
// MFMA flash attention partial. 32 q-rows/block (2 waves x 16), 32-key tiles.
// K/V pre-swizzled to fragment order: tile j0's K blob = Kz[j0*256 .. +8192),
// V blob = Vz[j0*256 .. +8192). Staging + fragment reads are linear b128.
__global__ __launch_bounds__(128, 2) void attn_mfma(
    const __hip_bfloat16* __restrict__ Qb, const __hip_bfloat16* __restrict__ Kz,
    const __hip_bfloat16* __restrict__ Vz, const float* __restrict__ maskG,
    float* __restrict__ PO, float* __restrict__ PM, float* __restrict__ PL,
    int M, int chunkKeys, int transposed)
{
    __shared__ unsigned short sKb[8192];      // 16 KB: 2 keytiles x 8 slices x 512
    __shared__ unsigned short sVb[8192];      // 16 KB: 16 dgroups x 512
    __shared__ unsigned short sP[2][16][40];
    __shared__ float          sMask[2][16][36];

    const int tid  = threadIdx.x;
    const int lane = tid & 63;
    const int wave = tid >> 6;
    const int col  = lane & 15;
    const int quad = lane >> 4;
    const int R0   = blockIdx.x * 32;
    const int split = blockIdx.y;
    const int jbase = split * chunkKeys;

    bf16x8 qf[8];
    {
        const __hip_bfloat16* qp =
            Qb + (size_t)(R0 + wave * 16 + col) * HD + quad * 8;
        #pragma unroll
        for (int s = 0; s < 8; ++s)
            qf[s] = *reinterpret_cast<const bf16x8*>(qp + 32 * s);
    }

    f32x4 o[16];
    #pragma unroll
    for (int dt = 0; dt < 16; ++dt) { o[dt][0]=0.f; o[dt][1]=0.f; o[dt][2]=0.f; o[dt][3]=0.f; }
    float m[4], l[4];
    #pragma unroll
    for (int r = 0; r < 4; ++r) { m[r] = -INFINITY; l[r] = 0.f; }

    for (int jt = 0; jt < chunkKeys; jt += 32) {
        const int j0 = jbase + jt;
        __syncthreads();
        // ---- stage K blob + V blob (contiguous 16 KB each, b128) ----
        {
            const uint4* ksrc = reinterpret_cast<const uint4*>(Kz + (size_t)j0 * 256);
            const uint4* vsrc = reinterpret_cast<const uint4*>(Vz + (size_t)j0 * 256);
            uint4* kdst = reinterpret_cast<uint4*>(sKb);
            uint4* vdst = reinterpret_cast<uint4*>(sVb);
            #pragma unroll
            for (int i = 0; i < 8; ++i) {
                kdst[tid + 128 * i] = ksrc[tid + 128 * i];
                vdst[tid + 128 * i] = vsrc[tid + 128 * i];
            }
        }
        // ---- stage mask tile per wave [16 rows][32 keys] ----
        if (!transposed) {
            const int row = lane >> 2;
            const int c0  = (lane & 3) * 8;
            #pragma unroll
            for (int i = 0; i < 2; ++i)
                *reinterpret_cast<float4*>(&sMask[wave][row][c0 + 4 * i]) =
                    *reinterpret_cast<const float4*>(
                        &maskG[(size_t)(R0 + wave * 16 + row) * N_REC + j0 + c0 + 4 * i]);
        } else {
            const int key = lane >> 1;
            const int rb  = (lane & 1) * 8;
            float tmp[8];
            #pragma unroll
            for (int i = 0; i < 2; ++i)
                *reinterpret_cast<float4*>(&tmp[4 * i]) =
                    *reinterpret_cast<const float4*>(
                        &maskG[(size_t)(j0 + key) * N_REC + R0 + wave * 16 + rb + 4 * i]);
            #pragma unroll
            for (int u = 0; u < 8; ++u)
                sMask[wave][rb + u][key] = tmp[u];
        }
        __syncthreads();

        // ---- S = Q K^T ----
        f32x4 sacc[2];
        sacc[0][0]=0.f; sacc[0][1]=0.f; sacc[0][2]=0.f; sacc[0][3]=0.f;
        sacc[1][0]=0.f; sacc[1][1]=0.f; sacc[1][2]=0.f; sacc[1][3]=0.f;
        #pragma unroll
        for (int t = 0; t < 2; ++t) {
            #pragma unroll
            for (int s = 0; s < 8; ++s) {
                bf16x8 kf = *reinterpret_cast<const bf16x8*>(
                    &sKb[(t * 8 + s) * 512 + lane * 8]);
                sacc[t] = __builtin_amdgcn_mfma_f32_16x16x32_bf16(qf[s], kf, sacc[t], 0, 0, 0);
            }
        }

        // ---- online softmax ----
        float a[2][4];
        #pragma unroll
        for (int t = 0; t < 2; ++t)
            #pragma unroll
            for (int r = 0; r < 4; ++r) {
                const float mv = sMask[wave][quad * 4 + r][col + 16 * t];
                a[t][r] = mv * sacc[t][r] - 1000.f * (1.f - mv);
            }
        #pragma unroll
        for (int r = 0; r < 4; ++r) {
            float mx = fmaxf(a[0][r], a[1][r]);
            #pragma unroll
            for (int off = 1; off < 16; off <<= 1)
                mx = fmaxf(mx, __shfl_xor(mx, off));
            const float mn = fmaxf(m[r], mx);
            const float c  = __expf(m[r] - mn);
            m[r] = mn;
            const float p0 = __expf(a[0][r] - mn);
            const float p1 = __expf(a[1][r] - mn);
            sP[wave][quad * 4 + r][col]      = f2bu(p0);
            sP[wave][quad * 4 + r][col + 16] = f2bu(p1);
            float ps = p0 + p1;
            #pragma unroll
            for (int off = 1; off < 16; off <<= 1)
                ps += __shfl_xor(ps, off);
            l[r] = l[r] * c + ps;
            #pragma unroll
            for (int dt = 0; dt < 16; ++dt) o[dt][r] *= c;
        }

        // ---- O += P V ----
        bf16x8 pf = *reinterpret_cast<const bf16x8*>(&sP[wave][col][quad * 8]);
        #pragma unroll
        for (int dt = 0; dt < 16; ++dt) {
            bf16x8 vf = *reinterpret_cast<const bf16x8*>(&sVb[dt * 512 + lane * 8]);
            o[dt] = __builtin_amdgcn_mfma_f32_16x16x32_bf16(pf, vf, o[dt], 0, 0, 0);
        }
    }

    #pragma unroll
    for (int dt = 0; dt < 16; ++dt)
        #pragma unroll
        for (int r = 0; r < 4; ++r) {
            const int row = R0 + wave * 16 + quad * 4 + r;
            PO[((size_t)split * M + row) * HD + dt * 16 + col] = o[dt][r];
        }
    if (col == 0) {
        #pragma unroll
        for (int r = 0; r < 4; ++r) {
            const int row = R0 + wave * 16 + quad * 4 + r;
            PM[(size_t)split * M + row] = m[r];
            PL[(size_t)split * M + row] = l[r];
        }
    }
}

// ---------------------------------------------------------------------------
__global__ void attn_combine(
    const float* __restrict__ PO, const float* __restrict__ PM,
    const float* __restrict__ PL, __hip_bfloat16* __restrict__ Out,
    int M, int nchunks)
{
    const int idx = blockIdx.x * 256 + threadIdx.x;
    const int row = idx >> 8;
    float mmax = -INFINITY;
    for (int c = 0; c < nchunks; ++c) mmax = fmaxf(mmax, PM[(size_t)c * M + row]);
    float denom = 0.f, acc = 0.f;
    for (int c = 0; c < nchunks; ++c) {
        const float w = __expf(PM[(size_t)c * M + row] - mmax);
        denom += PL[(size_t)c * M + row] * w;
        acc   += PO[(size_t)c * M * HD + idx] * w;
    }
    Out[idx] = __float2bfloat16(acc / denom);
}

// ---------------------------------------------------------------------------
__global__ void coords_fin(
    const float* __restrict__ coords, const float* __restrict__ origc,
    const float* __restrict__ xsum, const float* __restrict__ cnt,
    float* __restrict__ out, int n)
{
    const int i = blockIdx.x * 256 + threadIdx.x;
    if (i >= n * 3) return;
    const int node = i / 3;
    const float inv = 1.f / fmaxf(cnt[node], 1.f);
    out[i] = 0.25f * origc[i] + 0.75f * coords[i] + xsum[i] * inv;
}

// ---------------------------------------------------------------------------
extern "C" void kernel_launch(void* const* d_in, const int* in_sizes, int n_in,
                              void* d_out, int out_size, void* d_ws, size_t ws_size,
                              hipStream_t stream)
{
    const float* coords_lig = (const float*)d_in[0];
    const float* h_lig      = (const float*)d_in[1];
    const float* orig_lig   = (const float*)d_in[2];
    const float* origc_lig  = (const float*)d_in[3];
    const float* coords_rec = (const float*)d_in[4];
    const float* h_rec      = (const float*)d_in[5];
    const float* orig_rec   = (const float*)d_in[6];
    const float* origc_rec  = (const float*)d_in[7];
    const float* mask       = (const float*)d_in[8];
    const float* lig_ef     = (const float*)d_in[9];
    const float* rec_ef     = (const float*)d_in[10];
    const int* lig_src = (const int*)d_in[11];
    const int* lig_dst = (const int*)d_in[12];
    const int* rec_src = (const int*)d_in[13];
    const int* rec_dst = (const int*)d_in[14];
    const float* le_w1 = (const float*)d_in[15];
    const float* le_b1 = (const float*)d_in[16];
    const float* le_w2 = (const float*)d_in[17];
    const float* le_b2 = (const float*)d_in[18];
    const float* re_w1 = (const float*)d_in[19];
    const float* re_b1 = (const float*)d_in[20];
    const float* re_w2 = (const float*)d_in[21];
    const float* re_b2 = (const float*)d_in[22];
    const float* aql_w = (const float*)d_in[23];
    const float* akl_w = (const float*)d_in[24];
    const float* avl_w = (const float*)d_in[25];
    const float* aqr_w = (const float*)d_in[26];
    const float* akr_w = (const float*)d_in[27];
    const float* avr_w = (const float*)d_in[28];
    const float* nl_w1 = (const float*)d_in[29];
    const float* nl_b1 = (const float*)d_in[30];
    const float* nl_w2 = (const float*)d_in[31];
    const float* nl_b2 = (const float*)d_in[32];
    const float* nr_w1 = (const float*)d_in[33];
    const float* nr_b1 = (const float*)d_in[34];
    const float* nr_w2 = (const float*)d_in[35];
    const float* nr_b2 = (const float*)d_in[36];
    const float* cl_w1 = (const float*)d_in[37];
    const float* cl_b1 = (const float*)d_in[38];
    const float* cl_w2 = (const float*)d_in[39];
    const float* cl_b2 = (const float*)d_in[40];
    const float* cr_w1 = (const float*)d_in[41];
    const float* cr_b1 = (const float*)d_in[42];
    const float* cr_w2 = (const float*)d_in[43];
    const float* cr_b2 = (const float*)d_in[44];

    float* out = (float*)d_out;
    float* wsf = (float*)d_ws;

    // ---- fp32 accumulator zone (zeroed) ----
    const size_t AGGRL = 0;
    const size_t AGGRR = AGGRL + (size_t)N_LIG * HD;
    const size_t CNTL  = AGGRR + (size_t)N_REC * HD;
    const size_t CNTR  = CNTL + N_LIG;
    const size_t XSUML = CNTR + N_REC;
    const size_t XSUMR = XSUML + (size_t)N_LIG * 3;
    const size_t ZEND  = XSUMR + (size_t)N_REC * 3;

    // ---- bf16 zone ----
    __hip_bfloat16* wsb = (__hip_bfloat16*)(wsf + ZEND);
    const size_t QL  = 0;
    const size_t KL  = QL + (size_t)N_LIG * HD;
    const size_t VL  = KL + (size_t)N_LIG * HD;
    const size_t QR  = VL + (size_t)N_LIG * HD;
    const size_t KR  = QR + (size_t)N_REC * HD;
    const size_t VR  = KR + (size_t)N_REC * HD;
    const size_t CRL = VR + (size_t)N_REC * HD;
    const size_t CRR = CRL + (size_t)N_LIG * HD;
    const size_t KZL = CRR + (size_t)N_REC * HD;          // K swizzled lig
    const size_t VZL = KZL + (size_t)N_LIG * HD;          // V swizzled lig
    const size_t KZR = VZL + (size_t)N_LIG * HD;          // K swizzled rec
    const size_t VZR = KZR + (size_t)N_REC * HD;          // V swizzled rec
    const size_t EW1SZ = (size_t)16 * 17 * 512;
    const size_t KW256 = (size_t)16 * 8 * 512;
    const size_t NW1SZ = (size_t)16 * 18 * 512;
    const size_t SW_EL1 = VZR + (size_t)N_REC * HD;
    const size_t SW_EL2 = SW_EL1 + EW1SZ;
    const size_t SW_EC1 = SW_EL2 + KW256;
    const size_t SW_NL1 = SW_EC1 + KW256;
    const size_t SW_NL2 = SW_NL1 + NW1SZ;
    const size_t SW_ER1 = SW_NL2 + KW256;
    const size_t SW_ER2 = SW_ER1 + EW1SZ;
    const size_t SW_EC1R = SW_ER2 + KW256;
    const size_t SW_NR1 = SW_EC1R + KW256;
    const size_t SW_NR2 = SW_NR1 + NW1SZ;
    const size_t SW_PQL = SW_NR2 + KW256;
    const size_t SW_PKL = SW_PQL + KW256;
    const size_t SW_PVL = SW_PKL + KW256;
    const size_t SW_PQR = SW_PVL + KW256;
    const size_t SW_PKR = SW_PQR + KW256;
    const size_t SW_PVR = SW_PKR + KW256;
    const size_t BF_END = SW_PVR + KW256;

    // ---- split-K partial zone (fp32), dynamic splits ----
    float* wsp = (float*)(wsb + ((BF_END + 1) & ~(size_t)1));
    const size_t baseBytes = (size_t)((char*)wsp - (char*)d_ws);
    int SL = 16, SR = 4;
    {
        const size_t poElems16 = (size_t)16 * N_LIG * HD;
        const size_t need16 = baseBytes +
            (poElems16 + 2 * (size_t)16 * N_LIG) * sizeof(float);
        if (ws_size < need16) { SL = 8; SR = 2; }
    }
    const size_t PO_ = 0;
    const size_t PM_ = PO_ + (size_t)SL * N_LIG * HD;
    const size_t PL_ = PM_ + (size_t)SL * N_LIG;

    const size_t O_XL = 0;
    const size_t O_HL = O_XL + (size_t)N_LIG * 3;
    const size_t O_XR = O_HL + (size_t)N_LIG * HD;
    const size_t O_HR = O_XR + (size_t)N_REC * 3;

    // 1) zero atomic accumulators
    zero_kernel<<<((int)ZEND + 255) / 256, 256, 0, stream>>>(wsf, (int)ZEND);

    // 2) weight swizzles
    wt_swz<<<16 * 17, 256, 0, stream>>>(le_w1, wsb + SW_EL1, EIN, 17);
    wt_swz<<<16 * 8,  256, 0, stream>>>(le_w2, wsb + SW_EL2, 256, 8);
    wt_swz<<<16 * 8,  256, 0, stream>>>(cl_w1, wsb + SW_EC1, 256, 8);
    wt_swz<<<16 * 18, 256, 0, stream>>>(nl_w1, wsb + SW_NL1, 576, 18);
    wt_swz<<<16 * 8,  256, 0, stream>>>(nl_w2, wsb + SW_NL2, 256, 8);
    wt_swz<<<16 * 17, 256, 0, stream>>>(re_w1, wsb + SW_ER1, EIN, 17);
    wt_swz<<<16 * 8,  256, 0, stream>>>(re_w2, wsb + SW_ER2, 256, 8);
    wt_swz<<<16 * 8,  256, 0, stream>>>(cr_w1, wsb + SW_EC1R, 256, 8);
    wt_swz<<<16 * 18, 256, 0, stream>>>(nr_w1, wsb + SW_NR1, 576, 18);
    wt_swz<<<16 * 8,  256, 0, stream>>>(nr_w2, wsb + SW_NR2, 256, 8);
    wt_swz<<<16 * 8,  256, 0, stream>>>(aql_w, wsb + SW_PQL, 256, 8);
    wt_swz<<<16 * 8,  256, 0, stream>>>(akl_w, wsb + SW_PKL, 256, 8);
    wt_swz<<<16 * 8,  256, 0, stream>>>(avl_w, wsb + SW_PVL, 256, 8);
    wt_swz<<<16 * 8,  256, 0, stream>>>(aqr_w, wsb + SW_PQR, 256, 8);
    wt_swz<<<16 * 8,  256, 0, stream>>>(akr_w, wsb + SW_PKR, 256, 8);
    wt_swz<<<16 * 8,  256, 0, stream>>>(avr_w, wsb + SW_PVR, 256, 8);

    // 3) edge MFMA kernels
    edge_mfma<<<E_LIG_N / 32, 256, 0, stream>>>(
        coords_lig, h_lig, lig_ef, lig_src, lig_dst,
        wsb + SW_EL1, le_b1, wsb + SW_EL2, le_b2, wsb + SW_EC1, cl_b1, cl_w2, cl_b2,
        wsf + AGGRL, wsf + CNTL, wsf + XSUML);
    edge_mfma<<<E_REC_N / 32, 256, 0, stream>>>(
        coords_rec, h_rec, rec_ef, rec_src, rec_dst,
        wsb + SW_ER1, re_b1, wsb + SW_ER2, re_b2, wsb + SW_EC1R, cr_b1, cr_w2, cr_b2,
        wsf + AGGRR, wsf + CNTR, wsf + XSUMR);

    // 4) projections -> bf16 (MFMA), then K/V fragment swizzles
    proj_mfma<<<N_LIG / 32, 256, 0, stream>>>(h_lig, wsb + SW_PQL, wsb + QL, 1);
    proj_mfma<<<N_LIG / 32, 256, 0, stream>>>(h_lig, wsb + SW_PKL, wsb + KL, 1);
    proj_mfma<<<N_LIG / 32, 256, 0, stream>>>(h_lig, wsb + SW_PVL, wsb + VL, 0);
    proj_mfma<<<N_REC / 32, 256, 0, stream>>>(h_rec, wsb + SW_PQR, wsb + QR, 1);
    proj_mfma<<<N_REC / 32, 256, 0, stream>>>(h_rec, wsb + SW_PKR, wsb + KR, 1);
    proj_mfma<<<N_REC / 32, 256, 0, stream>>>(h_rec, wsb + SW_PVR, wsb + VR, 0);
    kswz_kernel<<<N_LIG / 8, 256, 0, stream>>>(wsb + KL, wsb + KZL);
    kswz_kernel<<<N_REC / 8, 256, 0, stream>>>(wsb + KR, wsb + KZR);
    vswz_kernel<<<N_LIG / 32, 256, 0, stream>>>(wsb + VL, wsb + VZL);
    vswz_kernel<<<N_REC / 32, 256, 0, stream>>>(wsb + VR, wsb + VZR);

    // 5) MFMA flash attention, split-K + combine
    {
        dim3 gl(N_LIG / 32, SL);
        attn_mfma<<<gl, 128, 0, stream>>>(wsb + QL, wsb + KZR, wsb + VZR, mask,
                                          wsp + PO_, wsp + PM_, wsp + PL_,
                                          N_LIG, N_REC / SL, 0);
        attn_combine<<<N_LIG, 256, 0, stream>>>(
            wsp + PO_, wsp + PM_, wsp + PL_, wsb + CRL, N_LIG, SL);

        dim3 gr(N_REC / 32, SR);
        attn_mfma<<<gr, 128, 0, stream>>>(wsb + QR, wsb + KZL, wsb + VZL, mask,
                                          wsp + PO_, wsp + PM_, wsp + PL_,
                                          N_REC, N_LIG / SR, 1);
        attn_combine<<<N_REC, 256, 0, stream>>>(
            wsp + PO_, wsp + PM_, wsp + PL_, wsb + CRR, N_REC, SR);
    }

    // 6) coordinate outputs
    coords_fin<<<(N_LIG * 3 + 255) / 256, 256, 0, stream>>>(
        coords_lig, origc_lig, wsf + XSUML, wsf + CNTL, out + O_XL, N_LIG);
    coords_fin<<<(N_REC * 3 + 255) / 256, 256, 0, stream>>>(
        coords_rec, origc_rec, wsf + XSUMR, wsf + CNTR, out + O_XR, N_REC);

    // 7) node MFMA kernels
    node_mfma<<<N_LIG / 32, 256, 0, stream>>>(
        wsf + AGGRL, wsf + CNTL, wsb + CRL, orig_lig, h_lig,
        wsb + SW_NL1, nl_b1, wsb + SW_NL2, nl_b2, out + O_HL);
    node_mfma<<<N_REC / 32, 256, 0, stream>>>(
        wsf + AGGRR, wsf + CNTR, wsb + CRR, orig_rec, h_rec,
        wsb + SW_NR1, nr_b1, wsb + SW_NR2, nr_b2, out + O_HR);

    (void)in_sizes; (void)n_in; (void)out_size;
}